// Round 2
// baseline (377756.372 us; speedup 1.0000x reference)
//
#include <hip/hip_runtime.h>

#define NN 16384
#define KP1 17
#define EE (NN*16)
#define FMAXV 3.402823466e+38f

// ---------------- h = pos @ W_in + b ----------------
__global__ __launch_bounds__(256) void k_lin_in(const float* __restrict__ pos,
    const float* __restrict__ W, const float* __restrict__ b, float* __restrict__ h) {
  const int t = blockIdx.x*256 + threadIdx.x;   // over N*64
  const int n = t >> 6, c = t & 63;
  float acc = b[c];
  #pragma unroll
  for (int k = 0; k < 11; ++k) acc = fmaf(pos[n*11+k], W[k*64+c], acc);
  h[t] = acc;
}

// ---------------- sq[n] = ||h[n]||^2 ----------------
__global__ __launch_bounds__(256) void k_sqnorm(const float* __restrict__ h, float* __restrict__ sq) {
  const int n = blockIdx.x*256 + threadIdx.x;
  const float4* row = (const float4*)(h + (size_t)n*64);
  float s = 0.f;
  #pragma unroll
  for (int q = 0; q < 16; ++q) { const float4 v = row[q]; s += v.x*v.x + v.y*v.y + v.z*v.z + v.w*v.w; }
  sq[n] = s;
}

// ---------------- ht[c][n] = h[n][c] ----------------
__global__ __launch_bounds__(256) void k_transpose(const float* __restrict__ h, float* __restrict__ ht) {
  const int t = blockIdx.x*256 + threadIdx.x;  // over N*16 float4s
  const int n = t >> 4, c4 = t & 15;
  const float4 v = ((const float4*)h)[t];
  ht[(size_t)(c4*4+0)*NN + n] = v.x;
  ht[(size_t)(c4*4+1)*NN + n] = v.y;
  ht[(size_t)(c4*4+2)*NN + n] = v.z;
  ht[(size_t)(c4*4+3)*NN + n] = v.w;
}

// ---------------- fused Gram + top-17, spill-free ----------------
// block = 256 threads = 64 rows x 4 col-sub-stripes (16 cols each); grid = N/64
__global__ __launch_bounds__(256, 4) void k_knn(const float* __restrict__ h,
    const float* __restrict__ ht, const float* __restrict__ sq, int* __restrict__ idxout) {
  __shared__ __align__(16) float at[64][68];   // own rows   [r][c]
  __shared__ __align__(16) float bt[64][68];   // col tile   [c][j]
  __shared__ float sqj[64];
  const int tid = threadIdx.x;
  const int sub = tid & 3;           // 4 stripes of 16 cols
  const int rl  = tid >> 2;          // local row 0..63
  const int r0  = blockIdx.x*64;
  const int jb  = sub*16;

  // stage A rows once (conflict-free: bank-quad (rl+c4)%8 even spread)
  #pragma unroll
  for (int l = 0; l < 4; ++l) {
    const int idx4 = l*256 + tid;
    const int ar = idx4 >> 4, ac4 = idx4 & 15;
    const float4 v = ((const float4*)h)[(size_t)(r0+ar)*16 + ac4];
    *(float4*)&at[ar][ac4*4] = v;
  }

  float val[KP1]; int vidx[KP1];
  #pragma unroll
  for (int p = 0; p < KP1; ++p) { val[p] = FMAXV; vidx[p] = 0; }

  for (int jt = 0; jt < NN/64; ++jt) {
    const int j0 = jt*64;
    // stage B tile transposed from ht (coalesced global, conflict-free LDS writes)
    #pragma unroll
    for (int l = 0; l < 4; ++l) {
      const int idx4 = l*256 + tid;
      const int c = idx4 >> 4, j4 = idx4 & 15;
      const float4 v = ((const float4*)ht)[(size_t)c*(NN/4) + (j0>>2) + j4];
      *(float4*)&bt[c][j4*4] = v;
    }
    if (tid < 64) sqj[tid] = sq[j0 + tid];
    __syncthreads();

    float acc[16];
    #pragma unroll
    for (int q = 0; q < 16; ++q) acc[q] = 0.f;

    #define DIMSTEP(CC, AV) { \
      const float4 b0 = *(const float4*)&bt[CC][jb]; \
      const float4 b1 = *(const float4*)&bt[CC][jb+4]; \
      const float4 b2 = *(const float4*)&bt[CC][jb+8]; \
      const float4 b3 = *(const float4*)&bt[CC][jb+12]; \
      acc[0]=fmaf(AV,b0.x,acc[0]);  acc[1]=fmaf(AV,b0.y,acc[1]); \
      acc[2]=fmaf(AV,b0.z,acc[2]);  acc[3]=fmaf(AV,b0.w,acc[3]); \
      acc[4]=fmaf(AV,b1.x,acc[4]);  acc[5]=fmaf(AV,b1.y,acc[5]); \
      acc[6]=fmaf(AV,b1.z,acc[6]);  acc[7]=fmaf(AV,b1.w,acc[7]); \
      acc[8]=fmaf(AV,b2.x,acc[8]);  acc[9]=fmaf(AV,b2.y,acc[9]); \
      acc[10]=fmaf(AV,b2.z,acc[10]); acc[11]=fmaf(AV,b2.w,acc[11]); \
      acc[12]=fmaf(AV,b3.x,acc[12]); acc[13]=fmaf(AV,b3.y,acc[13]); \
      acc[14]=fmaf(AV,b3.z,acc[14]); acc[15]=fmaf(AV,b3.w,acc[15]); }

    #pragma unroll
    for (int c4 = 0; c4 < 16; ++c4) {
      const float4 av = *(const float4*)&at[rl][c4*4];
      DIMSTEP(c4*4+0, av.x)
      DIMSTEP(c4*4+1, av.y)
      DIMSTEP(c4*4+2, av.z)
      DIMSTEP(c4*4+3, av.w)
    }
    #undef DIMSTEP

    // rank key = sq_j - 2*dot (monotone in d per row); keep 17 smallest, ties->lower index
    #pragma unroll
    for (int q = 0; q < 16; ++q) {
      const float key = fmaf(-2.f, acc[q], sqj[jb+q]);
      if (key < val[KP1-1]) {
        const int jg = j0 + jb + q;
        #pragma unroll
        for (int p = KP1-1; p > 0; --p) {
          if (val[p-1] > key)    { val[p] = val[p-1]; vidx[p] = vidx[p-1]; }
          else if (val[p] > key) { val[p] = key;      vidx[p] = jg; }
        }
        if (val[0] > key) { val[0] = key; vidx[0] = jg; }
      }
    }
    __syncthreads();
  }

  // merge 4 sorted partial lists per row; reuse at/bt LDS (exactly 4352 floats each)
  float* mv = &at[0][0];
  int*   mi = (int*)&bt[0][0];
  #pragma unroll
  for (int p = 0; p < KP1; ++p) {
    mv[rl*68 + sub*KP1 + p] = val[p];
    mi[rl*68 + sub*KP1 + p] = vidx[p];
  }
  __syncthreads();
  if (sub == 0) {
    int hh0=0,hh1=0,hh2=0,hh3=0;
    for (int p = 0; p < KP1; ++p) {
      float bv = FMAXV; int bi = 0x7fffffff; int bs = -1;
      #define MCAND(S, HS) { if (HS < KP1) { const float v = mv[rl*68 + S*KP1 + HS]; \
          const int ix = mi[rl*68 + S*KP1 + HS]; \
          if (v < bv || (v == bv && ix < bi)) { bv = v; bi = ix; bs = S; } } }
      MCAND(0, hh0) MCAND(1, hh1) MCAND(2, hh2) MCAND(3, hh3)
      #undef MCAND
      idxout[(r0+rl)*KP1 + p] = bi;
      hh0 += (bs==0); hh1 += (bs==1); hh2 += (bs==2); hh3 += (bs==3);
    }
  }
}

// ---------------- column stats (sum, sumsq) ----------------
__global__ __launch_bounds__(256) void k_colstats(const float* __restrict__ x, const int rows,
    float* __restrict__ s, float* __restrict__ s2) {
  __shared__ float ls[4][64], ls2[4][64];
  const int tid = threadIdx.x;
  const int c = tid & 63, g = tid >> 6;
  float a = 0.f, b = 0.f;
  for (int r = blockIdx.x*4 + g; r < rows; r += 1024) {
    const float v = x[(size_t)r*64 + c];
    a += v; b = fmaf(v, v, b);
  }
  ls[g][c] = a; ls2[g][c] = b;
  __syncthreads();
  if (tid < 64) {
    atomicAdd(&s[tid],  ls[0][tid]+ls[1][tid]+ls[2][tid]+ls[3][tid]);
    atomicAdd(&s2[tid], ls2[0][tid]+ls2[1][tid]+ls2[2][tid]+ls2[3][tid]);
  }
}

// 64-col FMA against LDS weight row (broadcast reads)
__device__ __forceinline__ void fmarow(float (&acc)[64], const float (*ws)[64], int kk, float xv) {
  #pragma unroll
  for (int cq = 0; cq < 16; ++cq) {
    const float4 w4 = *(const float4*)&ws[kk][cq*4];
    acc[cq*4]   = fmaf(xv, w4.x, acc[cq*4]);
    acc[cq*4+1] = fmaf(xv, w4.y, acc[cq*4+1]);
    acc[cq*4+2] = fmaf(xv, w4.z, acc[cq*4+2]);
    acc[cq*4+3] = fmaf(xv, w4.w, acc[cq*4+3]);
  }
}

// ---------------- msg linear-1: y = [h[to] | h[frm]] @ W1 + b1 ----------------
__global__ __launch_bounds__(256) void k_mlpA_gather(const float* __restrict__ h,
    const int* __restrict__ idx, const float* __restrict__ W1, const float* __restrict__ b1,
    float* __restrict__ y) {
  __shared__ __align__(16) float ws[128][64];
  const int tid = threadIdx.x;
  for (int t = tid; t < 128*64/4; t += 256) ((float4*)ws)[t] = ((const float4*)W1)[t];
  __syncthreads();
  const int e = blockIdx.x*256 + tid;
  const int i = e & (NN-1);
  const int k = e >> 14;
  const int to = idx[i*KP1 + k + 1];
  const int fr = idx[i*KP1];
  float acc[64];
  #pragma unroll
  for (int c = 0; c < 64; ++c) acc[c] = b1[c];
  const float4* xa = (const float4*)(h + (size_t)to*64);
  #pragma unroll 2
  for (int kb = 0; kb < 16; ++kb) {
    const float4 x4 = xa[kb];
    fmarow(acc, ws, kb*4,   x4.x); fmarow(acc, ws, kb*4+1, x4.y);
    fmarow(acc, ws, kb*4+2, x4.z); fmarow(acc, ws, kb*4+3, x4.w);
  }
  const float4* xb = (const float4*)(h + (size_t)fr*64);
  #pragma unroll 2
  for (int kb = 0; kb < 16; ++kb) {
    const float4 x4 = xb[kb];
    fmarow(acc, ws, 64+kb*4,   x4.x); fmarow(acc, ws, 64+kb*4+1, x4.y);
    fmarow(acc, ws, 64+kb*4+2, x4.z); fmarow(acc, ws, 64+kb*4+3, x4.w);
  }
  float4* yo = (float4*)(y + (size_t)e*64);
  #pragma unroll
  for (int q = 0; q < 16; ++q) yo[q] = make_float4(acc[4*q], acc[4*q+1], acc[4*q+2], acc[4*q+3]);
}

// ---------------- upd linear-1: y = [h | agg] @ W1 + b1 ----------------
__global__ __launch_bounds__(256) void k_mlpA_cat(const float* __restrict__ h,
    const float* __restrict__ agg, const float* __restrict__ W1, const float* __restrict__ b1,
    float* __restrict__ y) {
  __shared__ __align__(16) float ws[128][64];
  const int tid = threadIdx.x;
  for (int t = tid; t < 128*64/4; t += 256) ((float4*)ws)[t] = ((const float4*)W1)[t];
  __syncthreads();
  const int n = blockIdx.x*256 + tid;
  float acc[64];
  #pragma unroll
  for (int c = 0; c < 64; ++c) acc[c] = b1[c];
  const float4* xa = (const float4*)(h + (size_t)n*64);
  #pragma unroll 2
  for (int kb = 0; kb < 16; ++kb) {
    const float4 x4 = xa[kb];
    fmarow(acc, ws, kb*4,   x4.x); fmarow(acc, ws, kb*4+1, x4.y);
    fmarow(acc, ws, kb*4+2, x4.z); fmarow(acc, ws, kb*4+3, x4.w);
  }
  const float4* xb = (const float4*)(agg + (size_t)n*64);
  #pragma unroll 2
  for (int kb = 0; kb < 16; ++kb) {
    const float4 x4 = xb[kb];
    fmarow(acc, ws, 64+kb*4,   x4.x); fmarow(acc, ws, 64+kb*4+1, x4.y);
    fmarow(acc, ws, 64+kb*4+2, x4.z); fmarow(acc, ws, 64+kb*4+3, x4.w);
  }
  float4* yo = (float4*)(y + (size_t)n*64);
  #pragma unroll
  for (int q = 0; q < 16; ++q) yo[q] = make_float4(acc[4*q], acc[4*q+1], acc[4*q+2], acc[4*q+3]);
}

// ---------------- linear-2 with fused BN+ReLU on input, IN-PLACE on y ----------------
__global__ __launch_bounds__(256) void k_mlpB(float* __restrict__ y,
    const float* __restrict__ s, const float* __restrict__ s2,
    const float* __restrict__ g, const float* __restrict__ be,
    const float* __restrict__ W2, const float* __restrict__ b2, const float invR) {
  __shared__ __align__(16) float ws[64][64];
  __shared__ float sc[64], sh[64];
  const int tid = threadIdx.x;
  for (int t = tid; t < 64*64/4; t += 256) ((float4*)ws)[t] = ((const float4*)W2)[t];
  if (tid < 64) {
    const float m = s[tid]*invR;
    const float v = fmaxf(s2[tid]*invR - m*m, 0.f);
    const float scv = g[tid]*rsqrtf(v + 1e-5f);
    sc[tid] = scv; sh[tid] = be[tid] - m*scv;
  }
  __syncthreads();
  const int e = blockIdx.x*256 + tid;
  float acc[64];
  #pragma unroll
  for (int c = 0; c < 64; ++c) acc[c] = b2[c];
  const float4* yr = (const float4*)(y + (size_t)e*64);
  #pragma unroll 2
  for (int kb = 0; kb < 16; ++kb) {
    const float4 x4 = yr[kb];
    const int k0 = kb*4;
    fmarow(acc, ws, k0,   fmaxf(fmaf(x4.x, sc[k0],   sh[k0]),   0.f));
    fmarow(acc, ws, k0+1, fmaxf(fmaf(x4.y, sc[k0+1], sh[k0+1]), 0.f));
    fmarow(acc, ws, k0+2, fmaxf(fmaf(x4.z, sc[k0+2], sh[k0+2]), 0.f));
    fmarow(acc, ws, k0+3, fmaxf(fmaf(x4.w, sc[k0+3], sh[k0+3]), 0.f));
  }
  float4* yo = (float4*)(y + (size_t)e*64);
  #pragma unroll
  for (int q = 0; q < 16; ++q) yo[q] = make_float4(acc[4*q], acc[4*q+1], acc[4*q+2], acc[4*q+3]);
}

// ---------------- msg final BN+ReLU + scatter-add ----------------
__global__ __launch_bounds__(256) void k_msgC(const float* __restrict__ y,
    const float* __restrict__ s, const float* __restrict__ s2,
    const float* __restrict__ g, const float* __restrict__ be,
    const int* __restrict__ idx, float* __restrict__ agg, const float invR) {
  __shared__ float sc[64], sh[64];
  const int tid = threadIdx.x;
  if (tid < 64) {
    const float m = s[tid]*invR;
    const float v = fmaxf(s2[tid]*invR - m*m, 0.f);
    const float scv = g[tid]*rsqrtf(v + 1e-5f);
    sc[tid] = scv; sh[tid] = be[tid] - m*scv;
  }
  __syncthreads();
  const int t = blockIdx.x*256 + tid;    // over E*64
  const int e = t >> 6, c = t & 63;
  const int i = e & (NN-1), k = e >> 14;
  const int to = idx[i*KP1 + k + 1];
  const float v = fmaxf(fmaf(y[t], sc[c], sh[c]), 0.f);
  atomicAdd(&agg[(size_t)to*64 + c], v);
}

// ---------------- upd final BN+ReLU + residual ----------------
__global__ __launch_bounds__(256) void k_updC(const float* __restrict__ y,
    const float* __restrict__ s, const float* __restrict__ s2,
    const float* __restrict__ g, const float* __restrict__ be,
    float* __restrict__ h, const float invR) {
  __shared__ float sc[64], sh[64];
  const int tid = threadIdx.x;
  if (tid < 64) {
    const float m = s[tid]*invR;
    const float v = fmaxf(s2[tid]*invR - m*m, 0.f);
    const float scv = g[tid]*rsqrtf(v + 1e-5f);
    sc[tid] = scv; sh[tid] = be[tid] - m*scv;
  }
  __syncthreads();
  const int t = blockIdx.x*256 + tid;    // over N*64
  const int c = t & 63;
  h[t] += fmaxf(fmaf(y[t], sc[c], sh[c]), 0.f);
}

// ---------------- out = mean(h) @ predW + predb ----------------
__global__ void k_final(const float* __restrict__ hsum, const float* __restrict__ pW,
                        const float* __restrict__ pb, float* __restrict__ out) {
  const int c = threadIdx.x;   // 64
  float v = hsum[c] * (1.f/(float)NN) * pW[c];
  #pragma unroll
  for (int m = 32; m >= 1; m >>= 1) v += __shfl_xor(v, m, 64);
  if (c == 0) out[0] = v + pb[0];
}

extern "C" void kernel_launch(void* const* d_in, const int* in_sizes, int n_in,
                              void* d_out, int out_size, void* d_ws, size_t ws_size,
                              hipStream_t stream) {
  const float* pos   = (const float*)d_in[0];
  const float* linW  = (const float*)d_in[1];
  const float* linb  = (const float*)d_in[2];
  const float* predW = (const float*)d_in[3];
  const float* predb = (const float*)d_in[4];
  const float* mW1 = (const float*)d_in[5];
  const float* mb1 = (const float*)d_in[6];
  const float* mg1 = (const float*)d_in[7];
  const float* mbe1= (const float*)d_in[8];
  const float* mW2 = (const float*)d_in[9];
  const float* mb2 = (const float*)d_in[10];
  const float* mg2 = (const float*)d_in[11];
  const float* mbe2= (const float*)d_in[12];
  const float* uW1 = (const float*)d_in[13];
  const float* ub1 = (const float*)d_in[14];
  const float* ug1 = (const float*)d_in[15];
  const float* ube1= (const float*)d_in[16];
  const float* uW2 = (const float*)d_in[17];
  const float* ub2 = (const float*)d_in[18];
  const float* ug2 = (const float*)d_in[19];
  const float* ube2= (const float*)d_in[20];

  // workspace layout (~84 MB)
  float* h     = (float*)d_ws;                    // N*64
  float* sq    = h + (size_t)NN*64;               // N
  float* agg   = sq + NN;                         // N*64
  float* ubuf  = agg + (size_t)NN*64;             // N*64
  float* stats = ubuf + (size_t)NN*64;            // 640: 8x64 stat slots + 2x64 pool
  int*   idx   = (int*)(stats + 640);             // N*17
  float* yb    = (float*)(idx + (size_t)NN*KP1);  // E*64
  float* ht    = yb;                              // N*64 transposed h, aliased onto yb

  k_lin_in<<<NN*64/256, 256, 0, stream>>>(pos, linW, linb, h);
  for (int l = 0; l < 4; ++l) {
    k_sqnorm<<<NN/256, 256, 0, stream>>>(h, sq);
    k_transpose<<<NN*16/256, 256, 0, stream>>>(h, ht);
    k_knn<<<NN/64, 256, 0, stream>>>(h, ht, sq, idx);
    hipMemsetAsync(stats, 0, 640*sizeof(float), stream);
    hipMemsetAsync(agg, 0, (size_t)NN*64*sizeof(float), stream);
    // msg MLP over E edges
    k_mlpA_gather<<<EE/256, 256, 0, stream>>>(h, idx, mW1 + l*8192, mb1 + l*64, yb);
    k_colstats<<<256, 256, 0, stream>>>(yb, EE, stats, stats+64);
    k_mlpB<<<EE/256, 256, 0, stream>>>(yb, stats, stats+64, mg1 + l*64, mbe1 + l*64,
                                       mW2 + l*4096, mb2 + l*64, 1.f/(float)EE);
    k_colstats<<<256, 256, 0, stream>>>(yb, EE, stats+128, stats+192);
    k_msgC<<<EE*64/256, 256, 0, stream>>>(yb, stats+128, stats+192, mg2 + l*64, mbe2 + l*64,
                                          idx, agg, 1.f/(float)EE);
    // upd MLP over N nodes
    k_mlpA_cat<<<NN/256, 256, 0, stream>>>(h, agg, uW1 + l*8192, ub1 + l*64, ubuf);
    k_colstats<<<256, 256, 0, stream>>>(ubuf, NN, stats+256, stats+320);
    k_mlpB<<<NN/256, 256, 0, stream>>>(ubuf, stats+256, stats+320, ug1 + l*64, ube1 + l*64,
                                       uW2 + l*4096, ub2 + l*64, 1.f/(float)NN);
    k_colstats<<<256, 256, 0, stream>>>(ubuf, NN, stats+384, stats+448);
    k_updC<<<NN*64/256, 256, 0, stream>>>(ubuf, stats+384, stats+448, ug2 + l*64, ube2 + l*64,
                                          h, 1.f/(float)NN);
  }
  hipMemsetAsync(stats+512, 0, 128*sizeof(float), stream);
  k_colstats<<<256, 256, 0, stream>>>(h, NN, stats+512, stats+576);
  k_final<<<1, 64, 0, stream>>>(stats+512, predW, predb, (float*)d_out);
}

// Round 3
// 7531.279 us; speedup vs baseline: 50.1583x; 50.1583x over previous
//
#include <hip/hip_runtime.h>

#define NN 16384
#define KP1 17
#define EE (NN*16)
#define NSPL 8
#define SPL (NN/NSPL)
#define FMAXV 3.402823466e+38f

typedef short bf16x8 __attribute__((ext_vector_type(8)));
typedef float f32x16 __attribute__((ext_vector_type(16)));

__device__ __forceinline__ ushort f2bf(float f) {
  unsigned u = __float_as_uint(f);
  unsigned r = (u + 0x7fffu + ((u >> 16) & 1u)) >> 16;
  return (ushort)r;
}
__device__ __forceinline__ float bf2f(ushort s) { return __uint_as_float(((unsigned)s) << 16); }

__device__ __forceinline__ unsigned long long packkey(float v, int j) {
  unsigned int u = __float_as_uint(v);
  u = (u & 0x80000000u) ? ~u : (u | 0x80000000u);
  return ((unsigned long long)u << 32) | (unsigned int)j;
}

// ---------------- h = pos @ W_in + b ----------------
__global__ __launch_bounds__(256) void k_lin_in(const float* __restrict__ pos,
    const float* __restrict__ W, const float* __restrict__ b, float* __restrict__ h) {
  const int t = blockIdx.x*256 + threadIdx.x;   // over N*64
  const int n = t >> 6, c = t & 63;
  float acc = b[c];
  #pragma unroll
  for (int k = 0; k < 11; ++k) acc = fmaf(pos[n*11+k], W[k*64+c], acc);
  h[t] = acc;
}

// ---------------- sq[n] = ||h[n]||^2 ----------------
__global__ __launch_bounds__(256) void k_sqnorm(const float* __restrict__ h, float* __restrict__ sq) {
  const int n = blockIdx.x*256 + threadIdx.x;
  const float4* row = (const float4*)(h + (size_t)n*64);
  float s = 0.f;
  #pragma unroll
  for (int q = 0; q < 16; ++q) { const float4 v = row[q]; s += v.x*v.x + v.y*v.y + v.z*v.z + v.w*v.w; }
  sq[n] = s;
}

// ---------------- split h into bf16 hi/lo planes ----------------
__global__ __launch_bounds__(256) void k_split(const float* __restrict__ h,
    ushort* __restrict__ hi, ushort* __restrict__ lo) {
  const int t = blockIdx.x*256 + threadIdx.x;   // over N*64
  const float v = h[t];
  const ushort bh = f2bf(v);
  hi[t] = bh;
  lo[t] = f2bf(v - bf2f(bh));
}

// ---------------- MFMA Gram + per-lane top-17 over a candidate split ----------------
// 1 wave per block. Queries: 32 per block (C cols). Candidates: SPL per block (C rows), 32/tile.
// dot = hi*hi' + hi*lo' + lo*hi'  (split-bf16 ~ fp32). key = sq_j - 2*dot (monotone in d).
__global__ __launch_bounds__(64) void k_knn_mfma(const ushort* __restrict__ hb_hi,
    const ushort* __restrict__ hb_lo, const float* __restrict__ sq,
    unsigned long long* __restrict__ lists) {
  __shared__ unsigned long long lbuf[64][KP1];
  const int lane = threadIdx.x;
  const int qb = blockIdx.x & (NN/32 - 1);
  const int s  = blockIdx.x >> 9;              // blockIdx.x / (NN/32)
  const int q0 = qb*32;
  const int c_begin = s*SPL;
  const int nlo = lane & 31, lhi = lane >> 5;

  // B-frags (queries), loaded once: B[k][n] = H[q0+n][k]; lane: n=lane&31, k=(lane>>5)*8+r
  bf16x8 bh[4], bl[4];
  #pragma unroll
  for (int ks = 0; ks < 4; ++ks) {
    const size_t off = (size_t)(q0 + nlo)*64 + ks*16 + lhi*8;
    bh[ks] = *(const bf16x8*)(hb_hi + off);
    bl[ks] = *(const bf16x8*)(hb_lo + off);
  }

  float val[KP1]; int vidx[KP1];
  #pragma unroll
  for (int p = 0; p < KP1; ++p) { val[p] = FMAXV; vidx[p] = 0; }

  for (int ct = 0; ct < SPL/32; ++ct) {
    const int c0 = c_begin + ct*32;
    f32x16 acc;
    #pragma unroll
    for (int q = 0; q < 16; ++q) acc[q] = 0.f;
    #pragma unroll
    for (int ks = 0; ks < 4; ++ks) {
      const size_t off = (size_t)(c0 + nlo)*64 + ks*16 + lhi*8;
      const bf16x8 ah = *(const bf16x8*)(hb_hi + off);
      const bf16x8 al = *(const bf16x8*)(hb_lo + off);
      acc = __builtin_amdgcn_mfma_f32_32x32x16_bf16(ah, bh[ks], acc, 0, 0, 0);
      acc = __builtin_amdgcn_mfma_f32_32x32x16_bf16(ah, bl[ks], acc, 0, 0, 0);
      acc = __builtin_amdgcn_mfma_f32_32x32x16_bf16(al, bh[ks], acc, 0, 0, 0);
    }
    // sq for this lane's candidate rows: row(r) = (r&3) + 8*(r>>2) + 4*lhi
    float sqa[16];
    #pragma unroll
    for (int g = 0; g < 4; ++g) {
      const float4 v = *(const float4*)&sq[c0 + g*8 + 4*lhi];
      sqa[g*4] = v.x; sqa[g*4+1] = v.y; sqa[g*4+2] = v.z; sqa[g*4+3] = v.w;
    }
    // rank: ascending candidate index within lane; strict < keeps lower index on ties
    #pragma unroll
    for (int r = 0; r < 16; ++r) {
      const float key = fmaf(-2.f, acc[r], sqa[r]);
      if (key < val[KP1-1]) {
        const int jg = c0 + (r&3) + 8*(r>>2) + 4*lhi;
        #pragma unroll
        for (int p = KP1-1; p > 0; --p) {
          if (val[p-1] > key)    { val[p] = val[p-1]; vidx[p] = vidx[p-1]; }
          else if (val[p] > key) { val[p] = key;      vidx[p] = jg; }
        }
        if (val[0] > key) { val[0] = key; vidx[0] = jg; }
      }
    }
  }

  // pack + merge lane l with lane l+32 (same query column), write sorted 17-list
  #pragma unroll
  for (int p = 0; p < KP1; ++p) lbuf[lane][p] = packkey(val[p], vidx[p]);
  __syncthreads();
  if (lane < 32) {
    unsigned long long* outp = lists + ((size_t)s*NN + q0 + lane)*KP1;
    int ia = 0, ib = 0;
    #pragma unroll
    for (int p = 0; p < KP1; ++p) {
      const unsigned long long a = lbuf[lane][ia];
      const unsigned long long b = lbuf[lane+32][ib];
      if (a < b) { outp[p] = a; ++ia; } else { outp[p] = b; ++ib; }
    }
  }
}

// ---------------- merge NSPL sorted 17-lists per query -> idx ----------------
__global__ __launch_bounds__(256) void k_knn_merge(const unsigned long long* __restrict__ lists,
    int* __restrict__ idxout) {
  const int q = blockIdx.x*256 + threadIdx.x;
  unsigned long long best[KP1];
  #pragma unroll
  for (int p = 0; p < KP1; ++p) best[p] = ~0ULL;
  for (int s = 0; s < NSPL; ++s) {
    const unsigned long long* lp = lists + ((size_t)s*NN + q)*KP1;
    for (int p = 0; p < KP1; ++p) {
      const unsigned long long v = lp[p];
      if (v >= best[KP1-1]) break;    // sorted list: rest can't qualify
      #pragma unroll
      for (int t = KP1-1; t > 0; --t) {
        if (best[t-1] > v)    { best[t] = best[t-1]; }
        else if (best[t] > v) { best[t] = v; }
      }
      if (best[0] > v) best[0] = v;
    }
  }
  #pragma unroll
  for (int p = 0; p < KP1; ++p) idxout[q*KP1 + p] = (int)(best[p] & 0xffffffffULL);
}

// ---------------- column stats (sum, sumsq) ----------------
__global__ __launch_bounds__(256) void k_colstats(const float* __restrict__ x, const int rows,
    float* __restrict__ s, float* __restrict__ s2) {
  __shared__ float ls[4][64], ls2[4][64];
  const int tid = threadIdx.x;
  const int c = tid & 63, g = tid >> 6;
  float a = 0.f, b = 0.f;
  for (int r = blockIdx.x*4 + g; r < rows; r += 1024) {
    const float v = x[(size_t)r*64 + c];
    a += v; b = fmaf(v, v, b);
  }
  ls[g][c] = a; ls2[g][c] = b;
  __syncthreads();
  if (tid < 64) {
    atomicAdd(&s[tid],  ls[0][tid]+ls[1][tid]+ls[2][tid]+ls[3][tid]);
    atomicAdd(&s2[tid], ls2[0][tid]+ls2[1][tid]+ls2[2][tid]+ls2[3][tid]);
  }
}

// 64-col FMA against LDS weight row (broadcast reads)
__device__ __forceinline__ void fmarow(float (&acc)[64], const float (*ws)[64], int kk, float xv) {
  #pragma unroll
  for (int cq = 0; cq < 16; ++cq) {
    const float4 w4 = *(const float4*)&ws[kk][cq*4];
    acc[cq*4]   = fmaf(xv, w4.x, acc[cq*4]);
    acc[cq*4+1] = fmaf(xv, w4.y, acc[cq*4+1]);
    acc[cq*4+2] = fmaf(xv, w4.z, acc[cq*4+2]);
    acc[cq*4+3] = fmaf(xv, w4.w, acc[cq*4+3]);
  }
}

// ---------------- msg linear-1: y = [h[to] | h[frm]] @ W1 + b1 ----------------
__global__ __launch_bounds__(256) void k_mlpA_gather(const float* __restrict__ h,
    const int* __restrict__ idx, const float* __restrict__ W1, const float* __restrict__ b1,
    float* __restrict__ y) {
  __shared__ __align__(16) float ws[128][64];
  const int tid = threadIdx.x;
  for (int t = tid; t < 128*64/4; t += 256) ((float4*)ws)[t] = ((const float4*)W1)[t];
  __syncthreads();
  const int e = blockIdx.x*256 + tid;
  const int i = e & (NN-1);
  const int k = e >> 14;
  const int to = idx[i*KP1 + k + 1];
  const int fr = idx[i*KP1];
  float acc[64];
  #pragma unroll
  for (int c = 0; c < 64; ++c) acc[c] = b1[c];
  const float4* xa = (const float4*)(h + (size_t)to*64);
  #pragma unroll 2
  for (int kb = 0; kb < 16; ++kb) {
    const float4 x4 = xa[kb];
    fmarow(acc, ws, kb*4,   x4.x); fmarow(acc, ws, kb*4+1, x4.y);
    fmarow(acc, ws, kb*4+2, x4.z); fmarow(acc, ws, kb*4+3, x4.w);
  }
  const float4* xb = (const float4*)(h + (size_t)fr*64);
  #pragma unroll 2
  for (int kb = 0; kb < 16; ++kb) {
    const float4 x4 = xb[kb];
    fmarow(acc, ws, 64+kb*4,   x4.x); fmarow(acc, ws, 64+kb*4+1, x4.y);
    fmarow(acc, ws, 64+kb*4+2, x4.z); fmarow(acc, ws, 64+kb*4+3, x4.w);
  }
  float4* yo = (float4*)(y + (size_t)e*64);
  #pragma unroll
  for (int q = 0; q < 16; ++q) yo[q] = make_float4(acc[4*q], acc[4*q+1], acc[4*q+2], acc[4*q+3]);
}

// ---------------- upd linear-1: y = [h | agg] @ W1 + b1 ----------------
__global__ __launch_bounds__(256) void k_mlpA_cat(const float* __restrict__ h,
    const float* __restrict__ agg, const float* __restrict__ W1, const float* __restrict__ b1,
    float* __restrict__ y) {
  __shared__ __align__(16) float ws[128][64];
  const int tid = threadIdx.x;
  for (int t = tid; t < 128*64/4; t += 256) ((float4*)ws)[t] = ((const float4*)W1)[t];
  __syncthreads();
  const int n = blockIdx.x*256 + tid;
  float acc[64];
  #pragma unroll
  for (int c = 0; c < 64; ++c) acc[c] = b1[c];
  const float4* xa = (const float4*)(h + (size_t)n*64);
  #pragma unroll 2
  for (int kb = 0; kb < 16; ++kb) {
    const float4 x4 = xa[kb];
    fmarow(acc, ws, kb*4,   x4.x); fmarow(acc, ws, kb*4+1, x4.y);
    fmarow(acc, ws, kb*4+2, x4.z); fmarow(acc, ws, kb*4+3, x4.w);
  }
  const float4* xb = (const float4*)(agg + (size_t)n*64);
  #pragma unroll 2
  for (int kb = 0; kb < 16; ++kb) {
    const float4 x4 = xb[kb];
    fmarow(acc, ws, 64+kb*4,   x4.x); fmarow(acc, ws, 64+kb*4+1, x4.y);
    fmarow(acc, ws, 64+kb*4+2, x4.z); fmarow(acc, ws, 64+kb*4+3, x4.w);
  }
  float4* yo = (float4*)(y + (size_t)n*64);
  #pragma unroll
  for (int q = 0; q < 16; ++q) yo[q] = make_float4(acc[4*q], acc[4*q+1], acc[4*q+2], acc[4*q+3]);
}

// ---------------- linear-2 with fused BN+ReLU on input, IN-PLACE on y ----------------
__global__ __launch_bounds__(256) void k_mlpB(float* __restrict__ y,
    const float* __restrict__ s, const float* __restrict__ s2,
    const float* __restrict__ g, const float* __restrict__ be,
    const float* __restrict__ W2, const float* __restrict__ b2, const float invR) {
  __shared__ __align__(16) float ws[64][64];
  __shared__ float sc[64], sh[64];
  const int tid = threadIdx.x;
  for (int t = tid; t < 64*64/4; t += 256) ((float4*)ws)[t] = ((const float4*)W2)[t];
  if (tid < 64) {
    const float m = s[tid]*invR;
    const float v = fmaxf(s2[tid]*invR - m*m, 0.f);
    const float scv = g[tid]*rsqrtf(v + 1e-5f);
    sc[tid] = scv; sh[tid] = be[tid] - m*scv;
  }
  __syncthreads();
  const int e = blockIdx.x*256 + tid;
  float acc[64];
  #pragma unroll
  for (int c = 0; c < 64; ++c) acc[c] = b2[c];
  const float4* yr = (const float4*)(y + (size_t)e*64);
  #pragma unroll 2
  for (int kb = 0; kb < 16; ++kb) {
    const float4 x4 = yr[kb];
    const int k0 = kb*4;
    fmarow(acc, ws, k0,   fmaxf(fmaf(x4.x, sc[k0],   sh[k0]),   0.f));
    fmarow(acc, ws, k0+1, fmaxf(fmaf(x4.y, sc[k0+1], sh[k0+1]), 0.f));
    fmarow(acc, ws, k0+2, fmaxf(fmaf(x4.z, sc[k0+2], sh[k0+2]), 0.f));
    fmarow(acc, ws, k0+3, fmaxf(fmaf(x4.w, sc[k0+3], sh[k0+3]), 0.f));
  }
  float4* yo = (float4*)(y + (size_t)e*64);
  #pragma unroll
  for (int q = 0; q < 16; ++q) yo[q] = make_float4(acc[4*q], acc[4*q+1], acc[4*q+2], acc[4*q+3]);
}

// ---------------- msg final BN+ReLU + scatter-add ----------------
__global__ __launch_bounds__(256) void k_msgC(const float* __restrict__ y,
    const float* __restrict__ s, const float* __restrict__ s2,
    const float* __restrict__ g, const float* __restrict__ be,
    const int* __restrict__ idx, float* __restrict__ agg, const float invR) {
  __shared__ float sc[64], sh[64];
  const int tid = threadIdx.x;
  if (tid < 64) {
    const float m = s[tid]*invR;
    const float v = fmaxf(s2[tid]*invR - m*m, 0.f);
    const float scv = g[tid]*rsqrtf(v + 1e-5f);
    sc[tid] = scv; sh[tid] = be[tid] - m*scv;
  }
  __syncthreads();
  const int t = blockIdx.x*256 + tid;    // over E*64
  const int e = t >> 6, c = t & 63;
  const int i = e & (NN-1), k = e >> 14;
  const int to = idx[i*KP1 + k + 1];
  const float v = fmaxf(fmaf(y[t], sc[c], sh[c]), 0.f);
  atomicAdd(&agg[(size_t)to*64 + c], v);
}

// ---------------- upd final BN+ReLU + residual ----------------
__global__ __launch_bounds__(256) void k_updC(const float* __restrict__ y,
    const float* __restrict__ s, const float* __restrict__ s2,
    const float* __restrict__ g, const float* __restrict__ be,
    float* __restrict__ h, const float invR) {
  __shared__ float sc[64], sh[64];
  const int tid = threadIdx.x;
  if (tid < 64) {
    const float m = s[tid]*invR;
    const float v = fmaxf(s2[tid]*invR - m*m, 0.f);
    const float scv = g[tid]*rsqrtf(v + 1e-5f);
    sc[tid] = scv; sh[tid] = be[tid] - m*scv;
  }
  __syncthreads();
  const int t = blockIdx.x*256 + tid;    // over N*64
  const int c = t & 63;
  h[t] += fmaxf(fmaf(y[t], sc[c], sh[c]), 0.f);
}

// ---------------- out = mean(h) @ predW + predb ----------------
__global__ void k_final(const float* __restrict__ hsum, const float* __restrict__ pW,
                        const float* __restrict__ pb, float* __restrict__ out) {
  const int c = threadIdx.x;   // 64
  float v = hsum[c] * (1.f/(float)NN) * pW[c];
  #pragma unroll
  for (int m = 32; m >= 1; m >>= 1) v += __shfl_xor(v, m, 64);
  if (c == 0) out[0] = v + pb[0];
}

extern "C" void kernel_launch(void* const* d_in, const int* in_sizes, int n_in,
                              void* d_out, int out_size, void* d_ws, size_t ws_size,
                              hipStream_t stream) {
  const float* pos   = (const float*)d_in[0];
  const float* linW  = (const float*)d_in[1];
  const float* linb  = (const float*)d_in[2];
  const float* predW = (const float*)d_in[3];
  const float* predb = (const float*)d_in[4];
  const float* mW1 = (const float*)d_in[5];
  const float* mb1 = (const float*)d_in[6];
  const float* mg1 = (const float*)d_in[7];
  const float* mbe1= (const float*)d_in[8];
  const float* mW2 = (const float*)d_in[9];
  const float* mb2 = (const float*)d_in[10];
  const float* mg2 = (const float*)d_in[11];
  const float* mbe2= (const float*)d_in[12];
  const float* uW1 = (const float*)d_in[13];
  const float* ub1 = (const float*)d_in[14];
  const float* ug1 = (const float*)d_in[15];
  const float* ube1= (const float*)d_in[16];
  const float* uW2 = (const float*)d_in[17];
  const float* ub2 = (const float*)d_in[18];
  const float* ug2 = (const float*)d_in[19];
  const float* ube2= (const float*)d_in[20];

  // workspace layout (~80 MB)
  float* h     = (float*)d_ws;                    // N*64
  float* sq    = h + (size_t)NN*64;               // N
  float* agg   = sq + NN;                         // N*64
  float* ubuf  = agg + (size_t)NN*64;             // N*64
  float* stats = ubuf + (size_t)NN*64;            // 640
  int*   idx   = (int*)(stats + 640);             // N*17
  float* yb    = (float*)(idx + (size_t)NN*KP1);  // E*64 fp32 (67 MB)
  // knn-phase scratch aliased into yb (dead once MLP phase writes yb)
  unsigned long long* lists = (unsigned long long*)yb;          // NSPL*N*17 u64 (17.8 MB)
  ushort* hb_hi = (ushort*)(lists + (size_t)NSPL*NN*KP1);       // N*64 bf16
  ushort* hb_lo = hb_hi + (size_t)NN*64;                        // N*64 bf16

  k_lin_in<<<NN*64/256, 256, 0, stream>>>(pos, linW, linb, h);
  for (int l = 0; l < 4; ++l) {
    k_sqnorm<<<NN/256, 256, 0, stream>>>(h, sq);
    k_split<<<NN*64/256, 256, 0, stream>>>(h, hb_hi, hb_lo);
    k_knn_mfma<<<(NN/32)*NSPL, 64, 0, stream>>>(hb_hi, hb_lo, sq, lists);
    k_knn_merge<<<NN/256, 256, 0, stream>>>(lists, idx);
    hipMemsetAsync(stats, 0, 640*sizeof(float), stream);
    hipMemsetAsync(agg, 0, (size_t)NN*64*sizeof(float), stream);
    // msg MLP over E edges
    k_mlpA_gather<<<EE/256, 256, 0, stream>>>(h, idx, mW1 + l*8192, mb1 + l*64, yb);
    k_colstats<<<256, 256, 0, stream>>>(yb, EE, stats, stats+64);
    k_mlpB<<<EE/256, 256, 0, stream>>>(yb, stats, stats+64, mg1 + l*64, mbe1 + l*64,
                                       mW2 + l*4096, mb2 + l*64, 1.f/(float)EE);
    k_colstats<<<256, 256, 0, stream>>>(yb, EE, stats+128, stats+192);
    k_msgC<<<EE*64/256, 256, 0, stream>>>(yb, stats+128, stats+192, mg2 + l*64, mbe2 + l*64,
                                          idx, agg, 1.f/(float)EE);
    // upd MLP over N nodes
    k_mlpA_cat<<<NN/256, 256, 0, stream>>>(h, agg, uW1 + l*8192, ub1 + l*64, ubuf);
    k_colstats<<<256, 256, 0, stream>>>(ubuf, NN, stats+256, stats+320);
    k_mlpB<<<NN/256, 256, 0, stream>>>(ubuf, stats+256, stats+320, ug1 + l*64, ube1 + l*64,
                                       uW2 + l*4096, ub2 + l*64, 1.f/(float)NN);
    k_colstats<<<256, 256, 0, stream>>>(ubuf, NN, stats+384, stats+448);
    k_updC<<<NN*64/256, 256, 0, stream>>>(ubuf, stats+384, stats+448, ug2 + l*64, ube2 + l*64,
                                          h, 1.f/(float)NN);
  }
  hipMemsetAsync(stats+512, 0, 128*sizeof(float), stream);
  k_colstats<<<256, 256, 0, stream>>>(h, NN, stats+512, stats+576);
  k_final<<<1, 64, 0, stream>>>(stats+512, predW, predb, (float*)d_out);
}

// Round 4
// 4495.749 us; speedup vs baseline: 84.0252x; 1.6752x over previous
//
#include <hip/hip_runtime.h>

#define NN 16384
#define KP1 17
#define EE (NN*16)
#define QB 64
#define CAP 256

typedef short bf16x8 __attribute__((ext_vector_type(8)));
typedef float f32x16 __attribute__((ext_vector_type(16)));

__device__ __forceinline__ ushort f2bf(float f) {
  unsigned u = __float_as_uint(f);
  unsigned r = (u + 0x7fffu + ((u >> 16) & 1u)) >> 16;
  return (ushort)r;
}
__device__ __forceinline__ float bf2f(ushort s) { return __uint_as_float(((unsigned)s) << 16); }

// ---------------- h = pos @ W_in + b ----------------
__global__ __launch_bounds__(256) void k_lin_in(const float* __restrict__ pos,
    const float* __restrict__ W, const float* __restrict__ b, float* __restrict__ h) {
  const int t = blockIdx.x*256 + threadIdx.x;   // over N*64
  const int n = t >> 6, c = t & 63;
  float acc = b[c];
  #pragma unroll
  for (int k = 0; k < 11; ++k) acc = fmaf(pos[n*11+k], W[k*64+c], acc);
  h[t] = acc;
}

// ---------------- sq[n] = ||h[n]||^2 ----------------
__global__ __launch_bounds__(256) void k_sqnorm(const float* __restrict__ h, float* __restrict__ sq) {
  const int n = blockIdx.x*256 + threadIdx.x;
  const float4* row = (const float4*)(h + (size_t)n*64);
  float s = 0.f;
  #pragma unroll
  for (int q = 0; q < 16; ++q) { const float4 v = row[q]; s += v.x*v.x + v.y*v.y + v.z*v.z + v.w*v.w; }
  sq[n] = s;
}

// ---------------- build split-bf16 planes, 80-dim padded ----------------
// A row n: dims 0..63 = -2*h[n], dim 64 = sq[n], 65..79 = 0   (hi + lo residual planes)
// B row n: dims 0..63 =    h[n], dim 64 = 1.0,   65..79 = 0
// => MFMA acc = sq_j - 2*<h_j, h_q>  (the ranking key) directly.
__global__ __launch_bounds__(256) void k_prep(const float* __restrict__ h, const float* __restrict__ sq,
    ushort* __restrict__ a_hi, ushort* __restrict__ a_lo,
    ushort* __restrict__ b_hi, ushort* __restrict__ b_lo) {
  const int t = blockIdx.x*256 + threadIdx.x;   // over NN*20 quads
  const int n = t / 20, quad = t - n*20;
  float v0 = 0.f, v1 = 0.f, v2 = 0.f, v3 = 0.f;
  if (quad < 16) {
    const float4 x = ((const float4*)h)[(size_t)n*16 + quad];
    v0 = x.x; v1 = x.y; v2 = x.z; v3 = x.w;
  } else if (quad == 16) {
    v0 = sq[n];
  }
  // a-plane values
  float a0 = v0, a1 = v1, a2 = v2, a3 = v3;
  if (quad < 16) { a0 = -2.f*v0; a1 = -2.f*v1; a2 = -2.f*v2; a3 = -2.f*v3; }
  // b-plane values
  float c0 = v0, c1 = v1, c2 = v2, c3 = v3;
  if (quad == 16) c0 = 1.f;
  ushort4 ah, al, bh, bl;
  ah.x = f2bf(a0); al.x = f2bf(a0 - bf2f(ah.x));
  ah.y = f2bf(a1); al.y = f2bf(a1 - bf2f(ah.y));
  ah.z = f2bf(a2); al.z = f2bf(a2 - bf2f(ah.z));
  ah.w = f2bf(a3); al.w = f2bf(a3 - bf2f(ah.w));
  bh.x = f2bf(c0); bl.x = f2bf(c0 - bf2f(bh.x));
  bh.y = f2bf(c1); bl.y = f2bf(c1 - bf2f(bh.y));
  bh.z = f2bf(c2); bl.z = f2bf(c2 - bf2f(bh.z));
  bh.w = f2bf(c3); bl.w = f2bf(c3 - bf2f(bh.w));
  const size_t o = (size_t)n*80 + quad*4;
  *(ushort4*)(a_hi + o) = ah;
  *(ushort4*)(a_lo + o) = al;
  *(ushort4*)(b_hi + o) = bh;
  *(ushort4*)(b_lo + o) = bl;
}

// ---------------- 3-scan histogram exact top-17 ----------------
// block = 512 thr (8 waves): wave w -> query half g=w&1 (32 q), candidate quarter cq=w>>1.
// Scan1: 256-bin hist on key_u32>>24. Scan2: refine next 8 bits. Scan3: collect <= bound.
__global__ __launch_bounds__(512) void k_knn3(const ushort* __restrict__ a_hi,
    const ushort* __restrict__ a_lo, const ushort* __restrict__ b_hi,
    const ushort* __restrict__ b_lo,
    unsigned long long* __restrict__ coll, unsigned* __restrict__ cnts) {
  __shared__ unsigned hist[256][QB];
  __shared__ unsigned bin1[QB], below1[QB], bound[QB], ccnt[QB];
  const int tid = threadIdx.x;
  const int wave = tid >> 6, lane = tid & 63;
  const int g = wave & 1, cq = wave >> 1;
  const int qloc = g*32 + (lane & 31);
  const int q = blockIdx.x*QB + qloc;
  const int lhi = lane >> 5;

  for (int i = tid; i < 256*QB; i += 512) ((unsigned*)hist)[i] = 0;

  bf16x8 bhf[5], blf[5];
  #pragma unroll
  for (int ks = 0; ks < 5; ++ks) {
    const size_t off = (size_t)q*80 + ks*16 + lhi*8;
    bhf[ks] = *(const bf16x8*)(b_hi + off);
    blf[ks] = *(const bf16x8*)(b_lo + off);
  }
  __syncthreads();

  auto tilekeys = [&](int c0, unsigned (&u)[16]) {
    f32x16 acc;
    #pragma unroll
    for (int i = 0; i < 16; ++i) acc[i] = 0.f;
    #pragma unroll
    for (int ks = 0; ks < 5; ++ks) {
      const size_t off = (size_t)(c0 + (lane & 31))*80 + ks*16 + lhi*8;
      const bf16x8 ah = *(const bf16x8*)(a_hi + off);
      const bf16x8 al = *(const bf16x8*)(a_lo + off);
      acc = __builtin_amdgcn_mfma_f32_32x32x16_bf16(ah, bhf[ks], acc, 0, 0, 0);
      acc = __builtin_amdgcn_mfma_f32_32x32x16_bf16(ah, blf[ks], acc, 0, 0, 0);
      acc = __builtin_amdgcn_mfma_f32_32x32x16_bf16(al, bhf[ks], acc, 0, 0, 0);
    }
    #pragma unroll
    for (int r = 0; r < 16; ++r) {
      const unsigned x = __float_as_uint(acc[r]);
      u[r] = (x & 0x80000000u) ? ~x : (x | 0x80000000u);
    }
  };

  // ---- scan 1: level-1 histogram ----
  for (int t = 0; t < 128; ++t) {
    const int c0 = (cq*128 + t)*32;
    unsigned u[16]; tilekeys(c0, u);
    #pragma unroll
    for (int r = 0; r < 16; ++r) atomicAdd(&hist[u[r] >> 24][qloc], 1u);
  }
  __syncthreads();
  if (tid < QB) {
    unsigned c = 0, b = 0, bl_ = 0, fnd = 0;
    for (int i = 0; i < 256; ++i) {
      const unsigned nc = c + hist[i][tid];
      if (!fnd && nc >= KP1) { b = (unsigned)i; bl_ = c; fnd = 1; }
      c = nc;
    }
    bin1[tid] = b; below1[tid] = bl_;
  }
  __syncthreads();
  for (int i = tid; i < 256*QB; i += 512) ((unsigned*)hist)[i] = 0;
  __syncthreads();

  // ---- scan 2: level-2 histogram restricted to pivot bin ----
  const unsigned b1q = bin1[qloc];
  for (int t = 0; t < 128; ++t) {
    const int c0 = (cq*128 + t)*32;
    unsigned u[16]; tilekeys(c0, u);
    #pragma unroll
    for (int r = 0; r < 16; ++r)
      if ((u[r] >> 24) == b1q) atomicAdd(&hist[(u[r] >> 16) & 255u][qloc], 1u);
  }
  __syncthreads();
  if (tid < QB) {
    unsigned c = below1[tid], b = 255, fnd = 0;
    for (int i = 0; i < 256; ++i) {
      c += hist[i][tid];
      if (!fnd && c >= KP1) { b = (unsigned)i; fnd = 1; }
    }
    bound[tid] = (bin1[tid] << 24) | (b << 16) | 0xFFFFu;
    ccnt[tid] = 0;
  }
  __syncthreads();

  // ---- scan 3: collect (key, idx) <= bound ----
  const unsigned bq = bound[qloc];
  for (int t = 0; t < 128; ++t) {
    const int c0 = (cq*128 + t)*32;
    unsigned u[16]; tilekeys(c0, u);
    #pragma unroll
    for (int r = 0; r < 16; ++r) {
      if (u[r] <= bq) {
        const unsigned slot = atomicAdd(&ccnt[qloc], 1u);
        const int cidx = c0 + (r & 3) + 8*(r >> 2) + 4*lhi;
        if (slot < CAP)
          coll[(size_t)q*CAP + slot] = ((unsigned long long)u[r] << 32) | (unsigned)cidx;
      }
    }
  }
  __syncthreads();
  if (tid < QB) cnts[blockIdx.x*QB + tid] = min(ccnt[tid], (unsigned)CAP);
}

// ---------------- final select: top-17 of m collected, lex (key, idx) ----------------
__global__ __launch_bounds__(256) void k_select(const unsigned long long* __restrict__ coll,
    const unsigned* __restrict__ cnts, int* __restrict__ idxout) {
  const int q = blockIdx.x*256 + threadIdx.x;
  const int m = (int)cnts[q];
  const unsigned long long* cp = coll + (size_t)q*CAP;
  unsigned long long best[KP1];
  #pragma unroll
  for (int p = 0; p < KP1; ++p) best[p] = ~0ULL;
  for (int i = 0; i < m; ++i) {
    const unsigned long long v = cp[i];
    if (v < best[KP1-1]) {
      #pragma unroll
      for (int p = KP1-1; p > 0; --p) {
        if (best[p-1] > v)    best[p] = best[p-1];
        else if (best[p] > v) best[p] = v;
      }
      if (best[0] > v) best[0] = v;
    }
  }
  #pragma unroll
  for (int p = 0; p < KP1; ++p) idxout[q*KP1 + p] = (int)(best[p] & 0xffffffffu);
}

// ---------------- column stats (sum, sumsq) ----------------
__global__ __launch_bounds__(256) void k_colstats(const float* __restrict__ x, const int rows,
    float* __restrict__ s, float* __restrict__ s2) {
  __shared__ float ls[4][64], ls2[4][64];
  const int tid = threadIdx.x;
  const int c = tid & 63, g = tid >> 6;
  float a = 0.f, b = 0.f;
  for (int r = blockIdx.x*4 + g; r < rows; r += 1024) {
    const float v = x[(size_t)r*64 + c];
    a += v; b = fmaf(v, v, b);
  }
  ls[g][c] = a; ls2[g][c] = b;
  __syncthreads();
  if (tid < 64) {
    atomicAdd(&s[tid],  ls[0][tid]+ls[1][tid]+ls[2][tid]+ls[3][tid]);
    atomicAdd(&s2[tid], ls2[0][tid]+ls2[1][tid]+ls2[2][tid]+ls2[3][tid]);
  }
}

// 64-col FMA against LDS weight row (broadcast reads)
__device__ __forceinline__ void fmarow(float (&acc)[64], const float (*ws)[64], int kk, float xv) {
  #pragma unroll
  for (int cq = 0; cq < 16; ++cq) {
    const float4 w4 = *(const float4*)&ws[kk][cq*4];
    acc[cq*4]   = fmaf(xv, w4.x, acc[cq*4]);
    acc[cq*4+1] = fmaf(xv, w4.y, acc[cq*4+1]);
    acc[cq*4+2] = fmaf(xv, w4.z, acc[cq*4+2]);
    acc[cq*4+3] = fmaf(xv, w4.w, acc[cq*4+3]);
  }
}

// ---------------- msg linear-1: y = [h[to] | h[frm]] @ W1 + b1 ----------------
__global__ __launch_bounds__(256) void k_mlpA_gather(const float* __restrict__ h,
    const int* __restrict__ idx, const float* __restrict__ W1, const float* __restrict__ b1,
    float* __restrict__ y) {
  __shared__ __align__(16) float ws[128][64];
  const int tid = threadIdx.x;
  for (int t = tid; t < 128*64/4; t += 256) ((float4*)ws)[t] = ((const float4*)W1)[t];
  __syncthreads();
  const int e = blockIdx.x*256 + tid;
  const int i = e & (NN-1);
  const int k = e >> 14;
  const int to = idx[i*KP1 + k + 1];
  const int fr = idx[i*KP1];
  float acc[64];
  #pragma unroll
  for (int c = 0; c < 64; ++c) acc[c] = b1[c];
  const float4* xa = (const float4*)(h + (size_t)to*64);
  #pragma unroll 2
  for (int kb = 0; kb < 16; ++kb) {
    const float4 x4 = xa[kb];
    fmarow(acc, ws, kb*4,   x4.x); fmarow(acc, ws, kb*4+1, x4.y);
    fmarow(acc, ws, kb*4+2, x4.z); fmarow(acc, ws, kb*4+3, x4.w);
  }
  const float4* xb = (const float4*)(h + (size_t)fr*64);
  #pragma unroll 2
  for (int kb = 0; kb < 16; ++kb) {
    const float4 x4 = xb[kb];
    fmarow(acc, ws, 64+kb*4,   x4.x); fmarow(acc, ws, 64+kb*4+1, x4.y);
    fmarow(acc, ws, 64+kb*4+2, x4.z); fmarow(acc, ws, 64+kb*4+3, x4.w);
  }
  float4* yo = (float4*)(y + (size_t)e*64);
  #pragma unroll
  for (int q = 0; q < 16; ++q) yo[q] = make_float4(acc[4*q], acc[4*q+1], acc[4*q+2], acc[4*q+3]);
}

// ---------------- upd linear-1: y = [h | agg] @ W1 + b1 ----------------
__global__ __launch_bounds__(256) void k_mlpA_cat(const float* __restrict__ h,
    const float* __restrict__ agg, const float* __restrict__ W1, const float* __restrict__ b1,
    float* __restrict__ y) {
  __shared__ __align__(16) float ws[128][64];
  const int tid = threadIdx.x;
  for (int t = tid; t < 128*64/4; t += 256) ((float4*)ws)[t] = ((const float4*)W1)[t];
  __syncthreads();
  const int n = blockIdx.x*256 + tid;
  float acc[64];
  #pragma unroll
  for (int c = 0; c < 64; ++c) acc[c] = b1[c];
  const float4* xa = (const float4*)(h + (size_t)n*64);
  #pragma unroll 2
  for (int kb = 0; kb < 16; ++kb) {
    const float4 x4 = xa[kb];
    fmarow(acc, ws, kb*4,   x4.x); fmarow(acc, ws, kb*4+1, x4.y);
    fmarow(acc, ws, kb*4+2, x4.z); fmarow(acc, ws, kb*4+3, x4.w);
  }
  const float4* xb = (const float4*)(agg + (size_t)n*64);
  #pragma unroll 2
  for (int kb = 0; kb < 16; ++kb) {
    const float4 x4 = xb[kb];
    fmarow(acc, ws, 64+kb*4,   x4.x); fmarow(acc, ws, 64+kb*4+1, x4.y);
    fmarow(acc, ws, 64+kb*4+2, x4.z); fmarow(acc, ws, 64+kb*4+3, x4.w);
  }
  float4* yo = (float4*)(y + (size_t)n*64);
  #pragma unroll
  for (int q = 0; q < 16; ++q) yo[q] = make_float4(acc[4*q], acc[4*q+1], acc[4*q+2], acc[4*q+3]);
}

// ---------------- linear-2 with fused BN+ReLU on input, IN-PLACE on y ----------------
__global__ __launch_bounds__(256) void k_mlpB(float* __restrict__ y,
    const float* __restrict__ s, const float* __restrict__ s2,
    const float* __restrict__ g, const float* __restrict__ be,
    const float* __restrict__ W2, const float* __restrict__ b2, const float invR) {
  __shared__ __align__(16) float ws[64][64];
  __shared__ float sc[64], sh[64];
  const int tid = threadIdx.x;
  for (int t = tid; t < 64*64/4; t += 256) ((float4*)ws)[t] = ((const float4*)W2)[t];
  if (tid < 64) {
    const float m = s[tid]*invR;
    const float v = fmaxf(s2[tid]*invR - m*m, 0.f);
    const float scv = g[tid]*rsqrtf(v + 1e-5f);
    sc[tid] = scv; sh[tid] = be[tid] - m*scv;
  }
  __syncthreads();
  const int e = blockIdx.x*256 + tid;
  float acc[64];
  #pragma unroll
  for (int c = 0; c < 64; ++c) acc[c] = b2[c];
  const float4* yr = (const float4*)(y + (size_t)e*64);
  #pragma unroll 2
  for (int kb = 0; kb < 16; ++kb) {
    const float4 x4 = yr[kb];
    const int k0 = kb*4;
    fmarow(acc, ws, k0,   fmaxf(fmaf(x4.x, sc[k0],   sh[k0]),   0.f));
    fmarow(acc, ws, k0+1, fmaxf(fmaf(x4.y, sc[k0+1], sh[k0+1]), 0.f));
    fmarow(acc, ws, k0+2, fmaxf(fmaf(x4.z, sc[k0+2], sh[k0+2]), 0.f));
    fmarow(acc, ws, k0+3, fmaxf(fmaf(x4.w, sc[k0+3], sh[k0+3]), 0.f));
  }
  float4* yo = (float4*)(y + (size_t)e*64);
  #pragma unroll
  for (int q = 0; q < 16; ++q) yo[q] = make_float4(acc[4*q], acc[4*q+1], acc[4*q+2], acc[4*q+3]);
}

// ---------------- msg final BN+ReLU + scatter-add ----------------
__global__ __launch_bounds__(256) void k_msgC(const float* __restrict__ y,
    const float* __restrict__ s, const float* __restrict__ s2,
    const float* __restrict__ g, const float* __restrict__ be,
    const int* __restrict__ idx, float* __restrict__ agg, const float invR) {
  __shared__ float sc[64], sh[64];
  const int tid = threadIdx.x;
  if (tid < 64) {
    const float m = s[tid]*invR;
    const float v = fmaxf(s2[tid]*invR - m*m, 0.f);
    const float scv = g[tid]*rsqrtf(v + 1e-5f);
    sc[tid] = scv; sh[tid] = be[tid] - m*scv;
  }
  __syncthreads();
  const int t = blockIdx.x*256 + tid;    // over E*64
  const int e = t >> 6, c = t & 63;
  const int i = e & (NN-1), k = e >> 14;
  const int to = idx[i*KP1 + k + 1];
  const float v = fmaxf(fmaf(y[t], sc[c], sh[c]), 0.f);
  atomicAdd(&agg[(size_t)to*64 + c], v);
}

// ---------------- upd final BN+ReLU + residual ----------------
__global__ __launch_bounds__(256) void k_updC(const float* __restrict__ y,
    const float* __restrict__ s, const float* __restrict__ s2,
    const float* __restrict__ g, const float* __restrict__ be,
    float* __restrict__ h, const float invR) {
  __shared__ float sc[64], sh[64];
  const int tid = threadIdx.x;
  if (tid < 64) {
    const float m = s[tid]*invR;
    const float v = fmaxf(s2[tid]*invR - m*m, 0.f);
    const float scv = g[tid]*rsqrtf(v + 1e-5f);
    sc[tid] = scv; sh[tid] = be[tid] - m*scv;
  }
  __syncthreads();
  const int t = blockIdx.x*256 + tid;    // over N*64
  const int c = t & 63;
  h[t] += fmaxf(fmaf(y[t], sc[c], sh[c]), 0.f);
}

// ---------------- out = mean(h) @ predW + predb ----------------
__global__ void k_final(const float* __restrict__ hsum, const float* __restrict__ pW,
                        const float* __restrict__ pb, float* __restrict__ out) {
  const int c = threadIdx.x;   // 64
  float v = hsum[c] * (1.f/(float)NN) * pW[c];
  #pragma unroll
  for (int m = 32; m >= 1; m >>= 1) v += __shfl_xor(v, m, 64);
  if (c == 0) out[0] = v + pb[0];
}

extern "C" void kernel_launch(void* const* d_in, const int* in_sizes, int n_in,
                              void* d_out, int out_size, void* d_ws, size_t ws_size,
                              hipStream_t stream) {
  const float* pos   = (const float*)d_in[0];
  const float* linW  = (const float*)d_in[1];
  const float* linb  = (const float*)d_in[2];
  const float* predW = (const float*)d_in[3];
  const float* predb = (const float*)d_in[4];
  const float* mW1 = (const float*)d_in[5];
  const float* mb1 = (const float*)d_in[6];
  const float* mg1 = (const float*)d_in[7];
  const float* mbe1= (const float*)d_in[8];
  const float* mW2 = (const float*)d_in[9];
  const float* mb2 = (const float*)d_in[10];
  const float* mg2 = (const float*)d_in[11];
  const float* mbe2= (const float*)d_in[12];
  const float* uW1 = (const float*)d_in[13];
  const float* ub1 = (const float*)d_in[14];
  const float* ug1 = (const float*)d_in[15];
  const float* ube1= (const float*)d_in[16];
  const float* uW2 = (const float*)d_in[17];
  const float* ub2 = (const float*)d_in[18];
  const float* ug2 = (const float*)d_in[19];
  const float* ube2= (const float*)d_in[20];

  // workspace layout (~80 MB)
  float* h     = (float*)d_ws;                    // N*64
  float* sq    = h + (size_t)NN*64;               // N
  float* agg   = sq + NN;                         // N*64
  float* ubuf  = agg + (size_t)NN*64;             // N*64
  float* stats = ubuf + (size_t)NN*64;            // 640
  int*   idx   = (int*)(stats + 640);             // N*17
  float* yb    = (float*)(idx + (size_t)NN*KP1);  // E*64 fp32 (67 MB)
  // knn-phase scratch aliased into yb (dead once MLP phase writes yb): 44.1 MB
  ushort* a_hi = (ushort*)yb;                     // N*80 bf16
  ushort* a_lo = a_hi + (size_t)NN*80;
  ushort* b_hi = a_lo + (size_t)NN*80;
  ushort* b_lo = b_hi + (size_t)NN*80;
  unsigned long long* coll = (unsigned long long*)(b_lo + (size_t)NN*80); // N*CAP u64 (33.5 MB)
  unsigned* cnts = (unsigned*)(coll + (size_t)NN*CAP);                    // N u32

  k_lin_in<<<NN*64/256, 256, 0, stream>>>(pos, linW, linb, h);
  for (int l = 0; l < 4; ++l) {
    k_sqnorm<<<NN/256, 256, 0, stream>>>(h, sq);
    k_prep<<<NN*20/256, 256, 0, stream>>>(h, sq, a_hi, a_lo, b_hi, b_lo);
    k_knn3<<<NN/QB, 512, 0, stream>>>(a_hi, a_lo, b_hi, b_lo, coll, cnts);
    k_select<<<NN/256, 256, 0, stream>>>(coll, cnts, idx);
    hipMemsetAsync(stats, 0, 640*sizeof(float), stream);
    hipMemsetAsync(agg, 0, (size_t)NN*64*sizeof(float), stream);
    // msg MLP over E edges
    k_mlpA_gather<<<EE/256, 256, 0, stream>>>(h, idx, mW1 + l*8192, mb1 + l*64, yb);
    k_colstats<<<256, 256, 0, stream>>>(yb, EE, stats, stats+64);
    k_mlpB<<<EE/256, 256, 0, stream>>>(yb, stats, stats+64, mg1 + l*64, mbe1 + l*64,
                                       mW2 + l*4096, mb2 + l*64, 1.f/(float)EE);
    k_colstats<<<256, 256, 0, stream>>>(yb, EE, stats+128, stats+192);
    k_msgC<<<EE*64/256, 256, 0, stream>>>(yb, stats+128, stats+192, mg2 + l*64, mbe2 + l*64,
                                          idx, agg, 1.f/(float)EE);
    // upd MLP over N nodes
    k_mlpA_cat<<<NN/256, 256, 0, stream>>>(h, agg, uW1 + l*8192, ub1 + l*64, ubuf);
    k_colstats<<<256, 256, 0, stream>>>(ubuf, NN, stats+256, stats+320);
    k_mlpB<<<NN/256, 256, 0, stream>>>(ubuf, stats+256, stats+320, ug1 + l*64, ube1 + l*64,
                                       uW2 + l*4096, ub2 + l*64, 1.f/(float)NN);
    k_colstats<<<256, 256, 0, stream>>>(ubuf, NN, stats+384, stats+448);
    k_updC<<<NN*64/256, 256, 0, stream>>>(ubuf, stats+384, stats+448, ug2 + l*64, ube2 + l*64,
                                          h, 1.f/(float)NN);
  }
  hipMemsetAsync(stats+512, 0, 128*sizeof(float), stream);
  k_colstats<<<256, 256, 0, stream>>>(h, NN, stats+512, stats+576);
  k_final<<<1, 64, 0, stream>>>(stats+512, predW, predb, (float*)d_out);
}

// Round 5
// 3832.536 us; speedup vs baseline: 98.5656x; 1.1730x over previous
//
#include <hip/hip_runtime.h>

#define NN 16384
#define KP1 17
#define EE (NN*16)
#define CAP 448
#define FMAXV 3.402823466e+38f

typedef short bf16x8 __attribute__((ext_vector_type(8)));
typedef float f32x16 __attribute__((ext_vector_type(16)));

__device__ __forceinline__ ushort f2bf(float f) {
  unsigned u = __float_as_uint(f);
  unsigned r = (u + 0x7fffu + ((u >> 16) & 1u)) >> 16;
  return (ushort)r;
}
__device__ __forceinline__ float bf2f(ushort s) { return __uint_as_float(((unsigned)s) << 16); }

// ---------------- h = pos @ W_in + b ----------------
__global__ __launch_bounds__(256) void k_lin_in(const float* __restrict__ pos,
    const float* __restrict__ W, const float* __restrict__ b, float* __restrict__ h) {
  const int t = blockIdx.x*256 + threadIdx.x;   // over N*64
  const int n = t >> 6, c = t & 63;
  float acc = b[c];
  #pragma unroll
  for (int k = 0; k < 11; ++k) acc = fmaf(pos[n*11+k], W[k*64+c], acc);
  h[t] = acc;
}

// ---------------- sq[n] = ||h[n]||^2 ----------------
__global__ __launch_bounds__(256) void k_sqnorm(const float* __restrict__ h, float* __restrict__ sq) {
  const int n = blockIdx.x*256 + threadIdx.x;
  const float4* row = (const float4*)(h + (size_t)n*64);
  float s = 0.f;
  #pragma unroll
  for (int q = 0; q < 16; ++q) { const float4 v = row[q]; s += v.x*v.x + v.y*v.y + v.z*v.z + v.w*v.w; }
  sq[n] = s;
}

// ---------------- pack h into tile-major split-bf16 MFMA fragments ----------------
// pk[tile][ks][plane][lane][8]: lane l holds H[tile*32 + (l&31)][ks*16 + (l>>5)*8 + e]
// hi plane (0) + lo residual plane (1). One array serves A (candidates) AND B (queries).
__global__ __launch_bounds__(256) void k_prep(const float* __restrict__ h, ushort* __restrict__ pk) {
  const int t = blockIdx.x*256 + threadIdx.x;   // over (NN/32)*4*64
  const int lane = t & 63;
  const int ks = (t >> 6) & 3;
  const int tile = t >> 8;
  const int row = tile*32 + (lane & 31);
  const int kb = ks*16 + (lane >> 5)*8;
  const float4 x0 = *(const float4*)(h + (size_t)row*64 + kb);
  const float4 x1 = *(const float4*)(h + (size_t)row*64 + kb + 4);
  ushort4 h0, h1, l0, l1;
  h0.x = f2bf(x0.x); l0.x = f2bf(x0.x - bf2f(h0.x));
  h0.y = f2bf(x0.y); l0.y = f2bf(x0.y - bf2f(h0.y));
  h0.z = f2bf(x0.z); l0.z = f2bf(x0.z - bf2f(h0.z));
  h0.w = f2bf(x0.w); l0.w = f2bf(x0.w - bf2f(h0.w));
  h1.x = f2bf(x1.x); l1.x = f2bf(x1.x - bf2f(h1.x));
  h1.y = f2bf(x1.y); l1.y = f2bf(x1.y - bf2f(h1.y));
  h1.z = f2bf(x1.z); l1.z = f2bf(x1.z - bf2f(h1.z));
  h1.w = f2bf(x1.w); l1.w = f2bf(x1.w - bf2f(h1.w));
  const size_t base = (size_t)tile*4096 + ks*1024 + (size_t)lane*8;
  *(ushort4*)(pk + base)       = h0;
  *(ushort4*)(pk + base + 4)   = h1;
  *(ushort4*)(pk + base + 512)     = l0;
  *(ushort4*)(pk + base + 512 + 4) = l1;
}

#define LOADFRAG(dsth, dstl, TILE, KS) { \
  const ushort* tp_ = pk + (size_t)(TILE)*4096 + (KS)*1024 + (size_t)lane*8; \
  dsth = *(const bf16x8*)tp_; dstl = *(const bf16x8*)(tp_ + 512); }

// compute u32-ordered keys for one candidate tile (32 cands x lane's query col)
#define TILEKEYS(TILE, U) { \
  f32x16 acc_; \
  _Pragma("unroll") for (int i_ = 0; i_ < 16; ++i_) acc_[i_] = 0.f; \
  _Pragma("unroll") for (int ks_ = 0; ks_ < 4; ++ks_) { \
    bf16x8 ah_, al_; LOADFRAG(ah_, al_, TILE, ks_) \
    acc_ = __builtin_amdgcn_mfma_f32_32x32x16_bf16(ah_, bh[ks_], acc_, 0, 0, 0); \
    acc_ = __builtin_amdgcn_mfma_f32_32x32x16_bf16(ah_, bl[ks_], acc_, 0, 0, 0); \
    acc_ = __builtin_amdgcn_mfma_f32_32x32x16_bf16(al_, bh[ks_], acc_, 0, 0, 0); \
  } \
  const int c0_ = (TILE)*32; \
  float sqa_[16]; \
  _Pragma("unroll") for (int g_ = 0; g_ < 4; ++g_) { \
    const float4 v_ = *(const float4*)&sq[c0_ + g_*8 + 4*lhi]; \
    sqa_[g_*4] = v_.x; sqa_[g_*4+1] = v_.y; sqa_[g_*4+2] = v_.z; sqa_[g_*4+3] = v_.w; \
  } \
  _Pragma("unroll") for (int r_ = 0; r_ < 16; ++r_) { \
    const float key_ = fmaf(-2.f, acc_[r_], sqa_[r_]); \
    const unsigned x_ = __float_as_uint(key_); \
    U[r_] = (x_ & 0x80000000u) ? ~x_ : (x_ | 0x80000000u); \
  } }

// ---------------- bound kernel: exact count>=17 bound from 2048-cand subset ----------------
// grid = NN/32 blocks x 512 thr (8 waves). Wave w = candidate eighth. Queries: 32/block.
__global__ __launch_bounds__(512) void k_bound(const ushort* __restrict__ pk,
    const float* __restrict__ sq, unsigned* __restrict__ bounds) {
  __shared__ unsigned hist[256][32];
  __shared__ unsigned bin1s[32], below1s[32];
  const int tid = threadIdx.x;
  const int wave = tid >> 6, lane = tid & 63;
  const int ql = lane & 31, lhi = lane >> 5;
  const int qt = blockIdx.x;

  for (int i = tid; i < 256*32; i += 512) ((unsigned*)hist)[i] = 0;

  bf16x8 bh[4], bl[4];
  #pragma unroll
  for (int ks = 0; ks < 4; ++ks) LOADFRAG(bh[ks], bl[ks], qt, ks)
  __syncthreads();

  // scan 1: level-1 hist (top 8 bits) over subset tiles
  #pragma unroll 1
  for (int s = 0; s < 8; ++s) {
    const int tile = wave*8 + s;
    unsigned u[16]; TILEKEYS(tile, u)
    #pragma unroll
    for (int r = 0; r < 16; ++r) atomicAdd(&hist[u[r] >> 24][ql], 1u);
  }
  __syncthreads();
  if (tid < 32) {
    unsigned c = 0, b = 0, bl_ = 0, fnd = 0;
    for (int i = 0; i < 256; ++i) {
      const unsigned nc = c + hist[i][tid];
      if (!fnd && nc >= KP1) { b = (unsigned)i; bl_ = c; fnd = 1; }
      c = nc;
    }
    bin1s[tid] = b; below1s[tid] = bl_;
  }
  __syncthreads();
  for (int i = tid; i < 256*32; i += 512) ((unsigned*)hist)[i] = 0;
  __syncthreads();

  // scan 2: level-2 hist within pivot bin
  const unsigned b1 = bin1s[ql];
  #pragma unroll 1
  for (int s = 0; s < 8; ++s) {
    const int tile = wave*8 + s;
    unsigned u[16]; TILEKEYS(tile, u)
    #pragma unroll
    for (int r = 0; r < 16; ++r)
      if ((u[r] >> 24) == b1) atomicAdd(&hist[(u[r] >> 16) & 255u][ql], 1u);
  }
  __syncthreads();
  if (tid < 32) {
    unsigned c = below1s[tid], b = 255, fnd = 0;
    for (int i = 0; i < 256; ++i) {
      c += hist[i][tid];
      if (!fnd && c >= KP1) { b = (unsigned)i; fnd = 1; }
    }
    bounds[qt*32 + tid] = (bin1s[tid] << 24) | (b << 16) | 0xFFFFu;
  }
}

// ---------------- collect kernel: single full scan, gather keys <= bound ----------------
// grid = (NN/64)*4: qb = bid>>2, cpart = bid&3. 8 waves: g=w&1 (query half), cq=w>>1.
__global__ __launch_bounds__(512) void k_collect(const ushort* __restrict__ pk,
    const float* __restrict__ sq, const unsigned* __restrict__ bounds,
    unsigned long long* __restrict__ coll, unsigned* __restrict__ gcnt) {
  const int tid = threadIdx.x;
  const int wave = tid >> 6, lane = tid & 63;
  const int lhi = lane >> 5;
  const int qb = blockIdx.x >> 2, cpart = blockIdx.x & 3;
  const int g = wave & 1, cq = wave >> 1;
  const int qt = qb*2 + g;
  const int q = qt*32 + (lane & 31);

  bf16x8 bh[4], bl[4];
  #pragma unroll
  for (int ks = 0; ks < 4; ++ks) LOADFRAG(bh[ks], bl[ks], qt, ks)
  const unsigned bq = bounds[q];
  const int tbase = cpart*128 + cq*32;

  #pragma unroll 1
  for (int s = 0; s < 32; ++s) {
    const int tile = tbase + s;
    unsigned u[16]; TILEKEYS(tile, u)
    #pragma unroll
    for (int r = 0; r < 16; ++r) {
      if (u[r] <= bq) {
        const unsigned slot = atomicAdd(&gcnt[q], 1u);
        const int cidx = tile*32 + (r & 3) + 8*(r >> 2) + 4*lhi;
        if (slot < CAP)
          coll[(size_t)q*CAP + slot] = ((unsigned long long)u[r] << 32) | (unsigned)cidx;
      }
    }
  }
}

// ---------------- final select: top-17 of m collected, lex (key, idx) ----------------
__global__ __launch_bounds__(256) void k_select(const unsigned long long* __restrict__ coll,
    const unsigned* __restrict__ cnts, int* __restrict__ idxout) {
  const int q = blockIdx.x*256 + threadIdx.x;
  const int m = min((int)cnts[q], CAP);
  const unsigned long long* cp = coll + (size_t)q*CAP;
  unsigned long long best[KP1];
  #pragma unroll
  for (int p = 0; p < KP1; ++p) best[p] = ~0ULL;
  for (int i = 0; i < m; ++i) {
    const unsigned long long v = cp[i];
    if (v < best[KP1-1]) {
      #pragma unroll
      for (int p = KP1-1; p > 0; --p) {
        if (best[p-1] > v)    best[p] = best[p-1];
        else if (best[p] > v) best[p] = v;
      }
      if (best[0] > v) best[0] = v;
    }
  }
  #pragma unroll
  for (int p = 0; p < KP1; ++p) idxout[q*KP1 + p] = (int)(best[p] & 0xffffffffu);
}

// ---------------- column stats (sum, sumsq) ----------------
__global__ __launch_bounds__(256) void k_colstats(const float* __restrict__ x, const int rows,
    float* __restrict__ s, float* __restrict__ s2) {
  __shared__ float ls[4][64], ls2[4][64];
  const int tid = threadIdx.x;
  const int c = tid & 63, g = tid >> 6;
  float a = 0.f, b = 0.f;
  for (int r = blockIdx.x*4 + g; r < rows; r += 1024) {
    const float v = x[(size_t)r*64 + c];
    a += v; b = fmaf(v, v, b);
  }
  ls[g][c] = a; ls2[g][c] = b;
  __syncthreads();
  if (tid < 64) {
    atomicAdd(&s[tid],  ls[0][tid]+ls[1][tid]+ls[2][tid]+ls[3][tid]);
    atomicAdd(&s2[tid], ls2[0][tid]+ls2[1][tid]+ls2[2][tid]+ls2[3][tid]);
  }
}

// 64-col FMA against LDS weight row (broadcast reads)
__device__ __forceinline__ void fmarow(float (&acc)[64], const float (*ws)[64], int kk, float xv) {
  #pragma unroll
  for (int cq = 0; cq < 16; ++cq) {
    const float4 w4 = *(const float4*)&ws[kk][cq*4];
    acc[cq*4]   = fmaf(xv, w4.x, acc[cq*4]);
    acc[cq*4+1] = fmaf(xv, w4.y, acc[cq*4+1]);
    acc[cq*4+2] = fmaf(xv, w4.z, acc[cq*4+2]);
    acc[cq*4+3] = fmaf(xv, w4.w, acc[cq*4+3]);
  }
}

// ---------------- msg linear-1: y = [h[to] | h[frm]] @ W1 + b1 ----------------
__global__ __launch_bounds__(256) void k_mlpA_gather(const float* __restrict__ h,
    const int* __restrict__ idx, const float* __restrict__ W1, const float* __restrict__ b1,
    float* __restrict__ y) {
  __shared__ __align__(16) float ws[128][64];
  const int tid = threadIdx.x;
  for (int t = tid; t < 128*64/4; t += 256) ((float4*)ws)[t] = ((const float4*)W1)[t];
  __syncthreads();
  const int e = blockIdx.x*256 + tid;
  const int i = e & (NN-1);
  const int k = e >> 14;
  const int to = idx[i*KP1 + k + 1];
  const int fr = idx[i*KP1];
  float acc[64];
  #pragma unroll
  for (int c = 0; c < 64; ++c) acc[c] = b1[c];
  const float4* xa = (const float4*)(h + (size_t)to*64);
  #pragma unroll 2
  for (int kb = 0; kb < 16; ++kb) {
    const float4 x4 = xa[kb];
    fmarow(acc, ws, kb*4,   x4.x); fmarow(acc, ws, kb*4+1, x4.y);
    fmarow(acc, ws, kb*4+2, x4.z); fmarow(acc, ws, kb*4+3, x4.w);
  }
  const float4* xb = (const float4*)(h + (size_t)fr*64);
  #pragma unroll 2
  for (int kb = 0; kb < 16; ++kb) {
    const float4 x4 = xb[kb];
    fmarow(acc, ws, 64+kb*4,   x4.x); fmarow(acc, ws, 64+kb*4+1, x4.y);
    fmarow(acc, ws, 64+kb*4+2, x4.z); fmarow(acc, ws, 64+kb*4+3, x4.w);
  }
  float4* yo = (float4*)(y + (size_t)e*64);
  #pragma unroll
  for (int q = 0; q < 16; ++q) yo[q] = make_float4(acc[4*q], acc[4*q+1], acc[4*q+2], acc[4*q+3]);
}

// ---------------- upd linear-1: y = [h | agg] @ W1 + b1 ----------------
__global__ __launch_bounds__(256) void k_mlpA_cat(const float* __restrict__ h,
    const float* __restrict__ agg, const float* __restrict__ W1, const float* __restrict__ b1,
    float* __restrict__ y) {
  __shared__ __align__(16) float ws[128][64];
  const int tid = threadIdx.x;
  for (int t = tid; t < 128*64/4; t += 256) ((float4*)ws)[t] = ((const float4*)W1)[t];
  __syncthreads();
  const int n = blockIdx.x*256 + tid;
  float acc[64];
  #pragma unroll
  for (int c = 0; c < 64; ++c) acc[c] = b1[c];
  const float4* xa = (const float4*)(h + (size_t)n*64);
  #pragma unroll 2
  for (int kb = 0; kb < 16; ++kb) {
    const float4 x4 = xa[kb];
    fmarow(acc, ws, kb*4,   x4.x); fmarow(acc, ws, kb*4+1, x4.y);
    fmarow(acc, ws, kb*4+2, x4.z); fmarow(acc, ws, kb*4+3, x4.w);
  }
  const float4* xb = (const float4*)(agg + (size_t)n*64);
  #pragma unroll 2
  for (int kb = 0; kb < 16; ++kb) {
    const float4 x4 = xb[kb];
    fmarow(acc, ws, 64+kb*4,   x4.x); fmarow(acc, ws, 64+kb*4+1, x4.y);
    fmarow(acc, ws, 64+kb*4+2, x4.z); fmarow(acc, ws, 64+kb*4+3, x4.w);
  }
  float4* yo = (float4*)(y + (size_t)n*64);
  #pragma unroll
  for (int q = 0; q < 16; ++q) yo[q] = make_float4(acc[4*q], acc[4*q+1], acc[4*q+2], acc[4*q+3]);
}

// ---------------- linear-2 with fused BN+ReLU on input, IN-PLACE on y ----------------
__global__ __launch_bounds__(256) void k_mlpB(float* __restrict__ y,
    const float* __restrict__ s, const float* __restrict__ s2,
    const float* __restrict__ g, const float* __restrict__ be,
    const float* __restrict__ W2, const float* __restrict__ b2, const float invR) {
  __shared__ __align__(16) float ws[64][64];
  __shared__ float sc[64], sh[64];
  const int tid = threadIdx.x;
  for (int t = tid; t < 64*64/4; t += 256) ((float4*)ws)[t] = ((const float4*)W2)[t];
  if (tid < 64) {
    const float m = s[tid]*invR;
    const float v = fmaxf(s2[tid]*invR - m*m, 0.f);
    const float scv = g[tid]*rsqrtf(v + 1e-5f);
    sc[tid] = scv; sh[tid] = be[tid] - m*scv;
  }
  __syncthreads();
  const int e = blockIdx.x*256 + tid;
  float acc[64];
  #pragma unroll
  for (int c = 0; c < 64; ++c) acc[c] = b2[c];
  const float4* yr = (const float4*)(y + (size_t)e*64);
  #pragma unroll 2
  for (int kb = 0; kb < 16; ++kb) {
    const float4 x4 = yr[kb];
    const int k0 = kb*4;
    fmarow(acc, ws, k0,   fmaxf(fmaf(x4.x, sc[k0],   sh[k0]),   0.f));
    fmarow(acc, ws, k0+1, fmaxf(fmaf(x4.y, sc[k0+1], sh[k0+1]), 0.f));
    fmarow(acc, ws, k0+2, fmaxf(fmaf(x4.z, sc[k0+2], sh[k0+2]), 0.f));
    fmarow(acc, ws, k0+3, fmaxf(fmaf(x4.w, sc[k0+3], sh[k0+3]), 0.f));
  }
  float4* yo = (float4*)(y + (size_t)e*64);
  #pragma unroll
  for (int q = 0; q < 16; ++q) yo[q] = make_float4(acc[4*q], acc[4*q+1], acc[4*q+2], acc[4*q+3]);
}

// ---------------- msg final BN+ReLU + scatter-add ----------------
__global__ __launch_bounds__(256) void k_msgC(const float* __restrict__ y,
    const float* __restrict__ s, const float* __restrict__ s2,
    const float* __restrict__ g, const float* __restrict__ be,
    const int* __restrict__ idx, float* __restrict__ agg, const float invR) {
  __shared__ float sc[64], sh[64];
  const int tid = threadIdx.x;
  if (tid < 64) {
    const float m = s[tid]*invR;
    const float v = fmaxf(s2[tid]*invR - m*m, 0.f);
    const float scv = g[tid]*rsqrtf(v + 1e-5f);
    sc[tid] = scv; sh[tid] = be[tid] - m*scv;
  }
  __syncthreads();
  const int t = blockIdx.x*256 + tid;    // over E*64
  const int e = t >> 6, c = t & 63;
  const int i = e & (NN-1), k = e >> 14;
  const int to = idx[i*KP1 + k + 1];
  const float v = fmaxf(fmaf(y[t], sc[c], sh[c]), 0.f);
  atomicAdd(&agg[(size_t)to*64 + c], v);
}

// ---------------- upd final BN+ReLU + residual ----------------
__global__ __launch_bounds__(256) void k_updC(const float* __restrict__ y,
    const float* __restrict__ s, const float* __restrict__ s2,
    const float* __restrict__ g, const float* __restrict__ be,
    float* __restrict__ h, const float invR) {
  __shared__ float sc[64], sh[64];
  const int tid = threadIdx.x;
  if (tid < 64) {
    const float m = s[tid]*invR;
    const float v = fmaxf(s2[tid]*invR - m*m, 0.f);
    const float scv = g[tid]*rsqrtf(v + 1e-5f);
    sc[tid] = scv; sh[tid] = be[tid] - m*scv;
  }
  __syncthreads();
  const int t = blockIdx.x*256 + tid;    // over N*64
  const int c = t & 63;
  h[t] += fmaxf(fmaf(y[t], sc[c], sh[c]), 0.f);
}

// ---------------- out = mean(h) @ predW + predb ----------------
__global__ void k_final(const float* __restrict__ hsum, const float* __restrict__ pW,
                        const float* __restrict__ pb, float* __restrict__ out) {
  const int c = threadIdx.x;   // 64
  float v = hsum[c] * (1.f/(float)NN) * pW[c];
  #pragma unroll
  for (int m = 32; m >= 1; m >>= 1) v += __shfl_xor(v, m, 64);
  if (c == 0) out[0] = v + pb[0];
}

extern "C" void kernel_launch(void* const* d_in, const int* in_sizes, int n_in,
                              void* d_out, int out_size, void* d_ws, size_t ws_size,
                              hipStream_t stream) {
  const float* pos   = (const float*)d_in[0];
  const float* linW  = (const float*)d_in[1];
  const float* linb  = (const float*)d_in[2];
  const float* predW = (const float*)d_in[3];
  const float* predb = (const float*)d_in[4];
  const float* mW1 = (const float*)d_in[5];
  const float* mb1 = (const float*)d_in[6];
  const float* mg1 = (const float*)d_in[7];
  const float* mbe1= (const float*)d_in[8];
  const float* mW2 = (const float*)d_in[9];
  const float* mb2 = (const float*)d_in[10];
  const float* mg2 = (const float*)d_in[11];
  const float* mbe2= (const float*)d_in[12];
  const float* uW1 = (const float*)d_in[13];
  const float* ub1 = (const float*)d_in[14];
  const float* ug1 = (const float*)d_in[15];
  const float* ube1= (const float*)d_in[16];
  const float* uW2 = (const float*)d_in[17];
  const float* ub2 = (const float*)d_in[18];
  const float* ug2 = (const float*)d_in[19];
  const float* ube2= (const float*)d_in[20];

  // workspace layout (~80 MB, same extent as R4)
  float* h     = (float*)d_ws;                    // N*64
  float* sq    = h + (size_t)NN*64;               // N
  float* agg   = sq + NN;                         // N*64
  float* ubuf  = agg + (size_t)NN*64;             // N*64
  float* stats = ubuf + (size_t)NN*64;            // 640
  int*   idx   = (int*)(stats + 640);             // N*17
  float* yb    = (float*)(idx + (size_t)NN*KP1);  // E*64 fp32 (67 MB)
  // knn-phase scratch aliased into yb (dead once MLP phase writes yb): ~63 MB
  ushort* pk = (ushort*)yb;                                     // (N/32)*4096 bf16 = 4 MB
  unsigned long long* coll = (unsigned long long*)(pk + (size_t)(NN/32)*4096); // N*CAP u64
  unsigned* gcnt   = (unsigned*)(coll + (size_t)NN*CAP);        // N
  unsigned* bounds = gcnt + NN;                                 // N

  k_lin_in<<<NN*64/256, 256, 0, stream>>>(pos, linW, linb, h);
  for (int l = 0; l < 4; ++l) {
    k_sqnorm<<<NN/256, 256, 0, stream>>>(h, sq);
    k_prep<<<(NN/32)*4*64/256, 256, 0, stream>>>(h, pk);
    k_bound<<<NN/32, 512, 0, stream>>>(pk, sq, bounds);
    hipMemsetAsync(gcnt, 0, NN*sizeof(unsigned), stream);
    k_collect<<<(NN/64)*4, 512, 0, stream>>>(pk, sq, bounds, coll, gcnt);
    k_select<<<NN/256, 256, 0, stream>>>(coll, gcnt, idx);
    hipMemsetAsync(stats, 0, 640*sizeof(float), stream);
    hipMemsetAsync(agg, 0, (size_t)NN*64*sizeof(float), stream);
    // msg MLP over E edges
    k_mlpA_gather<<<EE/256, 256, 0, stream>>>(h, idx, mW1 + l*8192, mb1 + l*64, yb);
    k_colstats<<<256, 256, 0, stream>>>(yb, EE, stats, stats+64);
    k_mlpB<<<EE/256, 256, 0, stream>>>(yb, stats, stats+64, mg1 + l*64, mbe1 + l*64,
                                       mW2 + l*4096, mb2 + l*64, 1.f/(float)EE);
    k_colstats<<<256, 256, 0, stream>>>(yb, EE, stats+128, stats+192);
    k_msgC<<<EE*64/256, 256, 0, stream>>>(yb, stats+128, stats+192, mg2 + l*64, mbe2 + l*64,
                                          idx, agg, 1.f/(float)EE);
    // upd MLP over N nodes
    k_mlpA_cat<<<NN/256, 256, 0, stream>>>(h, agg, uW1 + l*8192, ub1 + l*64, ubuf);
    k_colstats<<<256, 256, 0, stream>>>(ubuf, NN, stats+256, stats+320);
    k_mlpB<<<NN/256, 256, 0, stream>>>(ubuf, stats+256, stats+320, ug1 + l*64, ube1 + l*64,
                                       uW2 + l*4096, ub2 + l*64, 1.f/(float)NN);
    k_colstats<<<256, 256, 0, stream>>>(ubuf, NN, stats+384, stats+448);
    k_updC<<<NN*64/256, 256, 0, stream>>>(ubuf, stats+384, stats+448, ug2 + l*64, ube2 + l*64,
                                          h, 1.f/(float)NN);
  }
  hipMemsetAsync(stats+512, 0, 128*sizeof(float), stream);
  k_colstats<<<256, 256, 0, stream>>>(h, NN, stats+512, stats+576);
  k_final<<<1, 64, 0, stream>>>(stats+512, predW, predb, (float*)d_out);
}

// Round 6
// 3075.630 us; speedup vs baseline: 122.8225x; 1.2461x over previous
//
#include <hip/hip_runtime.h>

#define NN 16384
#define KP1 17
#define EE (NN*16)
#define CAP 448

typedef short bf16x8 __attribute__((ext_vector_type(8)));
typedef float f32x16 __attribute__((ext_vector_type(16)));

__device__ __forceinline__ ushort f2bf(float f) {
  unsigned u = __float_as_uint(f);
  unsigned r = (u + 0x7fffu + ((u >> 16) & 1u)) >> 16;
  return (ushort)r;
}
__device__ __forceinline__ float bf2f(ushort s) { return __uint_as_float(((unsigned)s) << 16); }

// ---------------- h = pos @ W_in + b ----------------
__global__ __launch_bounds__(256) void k_lin_in(const float* __restrict__ pos,
    const float* __restrict__ W, const float* __restrict__ b, float* __restrict__ h) {
  const int t = blockIdx.x*256 + threadIdx.x;   // over N*64
  const int n = t >> 6, c = t & 63;
  float acc = b[c];
  #pragma unroll
  for (int k = 0; k < 11; ++k) acc = fmaf(pos[n*11+k], W[k*64+c], acc);
  h[t] = acc;
}

// ---------------- sq[n] = ||h[n]||^2 ----------------
__global__ __launch_bounds__(256) void k_sqnorm(const float* __restrict__ h, float* __restrict__ sq) {
  const int n = blockIdx.x*256 + threadIdx.x;
  const float4* row = (const float4*)(h + (size_t)n*64);
  float s = 0.f;
  #pragma unroll
  for (int q = 0; q < 16; ++q) { const float4 v = row[q]; s += v.x*v.x + v.y*v.y + v.z*v.z + v.w*v.w; }
  sq[n] = s;
}

// ---------------- pack h into tile-major split-bf16 MFMA fragments ----------------
// pk[tile][ks][plane][lane][8]: lane l holds H[tile*32 + (l&31)][ks*16 + (l>>5)*8 + e]
__global__ __launch_bounds__(256) void k_prep(const float* __restrict__ h, ushort* __restrict__ pk) {
  const int t = blockIdx.x*256 + threadIdx.x;   // over (NN/32)*4*64
  const int lane = t & 63;
  const int ks = (t >> 6) & 3;
  const int tile = t >> 8;
  const int row = tile*32 + (lane & 31);
  const int kb = ks*16 + (lane >> 5)*8;
  const float4 x0 = *(const float4*)(h + (size_t)row*64 + kb);
  const float4 x1 = *(const float4*)(h + (size_t)row*64 + kb + 4);
  ushort4 h0, h1, l0, l1;
  h0.x = f2bf(x0.x); l0.x = f2bf(x0.x - bf2f(h0.x));
  h0.y = f2bf(x0.y); l0.y = f2bf(x0.y - bf2f(h0.y));
  h0.z = f2bf(x0.z); l0.z = f2bf(x0.z - bf2f(h0.z));
  h0.w = f2bf(x0.w); l0.w = f2bf(x0.w - bf2f(h0.w));
  h1.x = f2bf(x1.x); l1.x = f2bf(x1.x - bf2f(h1.x));
  h1.y = f2bf(x1.y); l1.y = f2bf(x1.y - bf2f(h1.y));
  h1.z = f2bf(x1.z); l1.z = f2bf(x1.z - bf2f(h1.z));
  h1.w = f2bf(x1.w); l1.w = f2bf(x1.w - bf2f(h1.w));
  const size_t base = (size_t)tile*4096 + ks*1024 + (size_t)lane*8;
  *(ushort4*)(pk + base)       = h0;
  *(ushort4*)(pk + base + 4)   = h1;
  *(ushort4*)(pk + base + 512)     = l0;
  *(ushort4*)(pk + base + 512 + 4) = l1;
}

struct F8 { bf16x8 h0,h1,h2,h3,l0,l1,l2,l3; };

__device__ __forceinline__ void ldf(const ushort* __restrict__ pk, int tile, int lane, F8& f) {
  const ushort* tp = pk + (size_t)tile*4096 + (size_t)lane*8;
  f.h0 = *(const bf16x8*)(tp);
  f.l0 = *(const bf16x8*)(tp + 512);
  f.h1 = *(const bf16x8*)(tp + 1024);
  f.l1 = *(const bf16x8*)(tp + 1536);
  f.h2 = *(const bf16x8*)(tp + 2048);
  f.l2 = *(const bf16x8*)(tp + 2560);
  f.h3 = *(const bf16x8*)(tp + 3072);
  f.l3 = *(const bf16x8*)(tp + 3584);
}

#define MF(A,B,C) __builtin_amdgcn_mfma_f32_32x32x16_bf16(A,B,C,0,0,0)

// keys for one candidate tile: key[r] = sq_cand - 2*dot(cand, q)  (split-bf16 ~ fp32)
__device__ __forceinline__ void tile_keys(const F8& f, const bf16x8 (&bqh)[4], const bf16x8 (&bql)[4],
    const float* __restrict__ sq, const int tile, const int lhi, float (&key)[16]) {
  f32x16 acc;
  #pragma unroll
  for (int i = 0; i < 16; ++i) acc[i] = 0.f;
  acc = MF(f.h0, bqh[0], acc); acc = MF(f.h0, bql[0], acc); acc = MF(f.l0, bqh[0], acc);
  acc = MF(f.h1, bqh[1], acc); acc = MF(f.h1, bql[1], acc); acc = MF(f.l1, bqh[1], acc);
  acc = MF(f.h2, bqh[2], acc); acc = MF(f.h2, bql[2], acc); acc = MF(f.l2, bqh[2], acc);
  acc = MF(f.h3, bqh[3], acc); acc = MF(f.h3, bql[3], acc); acc = MF(f.l3, bqh[3], acc);
  const int c0 = tile*32;
  #pragma unroll
  for (int g = 0; g < 4; ++g) {
    const float4 v = *(const float4*)(sq + c0 + g*8 + 4*lhi);
    key[g*4+0] = fmaf(-2.f, acc[g*4+0], v.x);
    key[g*4+1] = fmaf(-2.f, acc[g*4+1], v.y);
    key[g*4+2] = fmaf(-2.f, acc[g*4+2], v.z);
    key[g*4+3] = fmaf(-2.f, acc[g*4+3], v.w);
  }
}

#define HIST1(K) { _Pragma("unroll") for (int r = 0; r < 16; ++r) { \
    unsigned x = __float_as_uint(K[r]); x = (x & 0x80000000u) ? ~x : (x | 0x80000000u); \
    atomicAdd(&hist[x >> 24][qcol], 1u); } }
#define HIST2(K) { _Pragma("unroll") for (int r = 0; r < 16; ++r) { \
    unsigned x = __float_as_uint(K[r]); x = (x & 0x80000000u) ? ~x : (x | 0x80000000u); \
    if ((x >> 24) == b1) atomicAdd(&hist[(x >> 16) & 255u][qcol], 1u); } }
#define COLLECT(K, TILE) { _Pragma("unroll") for (int r = 0; r < 16; ++r) { \
    if (K[r] <= bfq) { \
      unsigned x = __float_as_uint(K[r]); x = (x & 0x80000000u) ? ~x : (x | 0x80000000u); \
      const unsigned slot = atomicAdd(&ccnt[qcol], 1u); \
      if (slot < CAP) { \
        const int cidx = (TILE)*32 + (r & 3) + 8*(r >> 2) + 4*lhi; \
        coll[(size_t)q*CAP + slot] = ((unsigned long long)x << 32) | (unsigned)cidx; } } } }

// ---------------- merged bound + collect ----------------
// grid = NN/32 blocks x 512 thr (8 waves). Block owns 32 queries (one tile).
// Phase1/2: 2-level 256-bin hist over 2048-cand subset -> exact-valid bound.
// Phase3: full scan, wave w covers tiles [w*64, w*64+64), collect keys <= bound.
__global__ __launch_bounds__(512) void k_knn(const ushort* __restrict__ pk,
    const float* __restrict__ sq, unsigned long long* __restrict__ coll,
    unsigned* __restrict__ gcnt) {
  __shared__ unsigned hist[256][32];
  __shared__ unsigned bin1s[32], below1s[32];
  __shared__ float boundf[32];
  __shared__ unsigned ccnt[32];
  const int tid = threadIdx.x;
  const int wave = tid >> 6, lane = tid & 63;
  const int qcol = lane & 31, lhi = lane >> 5;
  const int qt = blockIdx.x;
  const int q = qt*32 + qcol;

  for (int i = tid; i < 256*32; i += 512) ((unsigned*)hist)[i] = 0u;
  if (tid < 32) ccnt[tid] = 0u;

  bf16x8 bqh[4], bql[4];
  {
    const ushort* tp = pk + (size_t)qt*4096 + (size_t)lane*8;
    #pragma unroll
    for (int ks = 0; ks < 4; ++ks) {
      bqh[ks] = *(const bf16x8*)(tp + ks*1024);
      bql[ks] = *(const bf16x8*)(tp + ks*1024 + 512);
    }
  }
  __syncthreads();

  // ---- phase 1: level-1 hist over subset tiles 0..63 (8 per wave) ----
  {
    F8 fa, fb;
    ldf(pk, wave*8, lane, fa);
    #pragma unroll 1
    for (int s = 0; s < 8; s += 2) {
      ldf(pk, wave*8 + s + 1, lane, fb);
      float k0[16]; tile_keys(fa, bqh, bql, sq, wave*8 + s, lhi, k0);
      HIST1(k0)
      if (s + 2 < 8) ldf(pk, wave*8 + s + 2, lane, fa);
      float k1[16]; tile_keys(fb, bqh, bql, sq, wave*8 + s + 1, lhi, k1);
      HIST1(k1)
    }
  }
  __syncthreads();
  if (tid < 32) {
    unsigned c = 0, b = 0, bl_ = 0, fnd = 0;
    #pragma unroll 1
    for (int i = 0; i < 256; ++i) {
      const unsigned nc = c + hist[i][tid];
      if (!fnd && nc >= KP1) { b = (unsigned)i; bl_ = c; fnd = 1; }
      c = nc;
    }
    bin1s[tid] = b; below1s[tid] = bl_;
  }
  __syncthreads();
  for (int i = tid; i < 256*32; i += 512) ((unsigned*)hist)[i] = 0u;
  __syncthreads();
  const unsigned b1 = bin1s[qcol];

  // ---- phase 2: level-2 hist within pivot bin ----
  {
    F8 fa, fb;
    ldf(pk, wave*8, lane, fa);
    #pragma unroll 1
    for (int s = 0; s < 8; s += 2) {
      ldf(pk, wave*8 + s + 1, lane, fb);
      float k0[16]; tile_keys(fa, bqh, bql, sq, wave*8 + s, lhi, k0);
      HIST2(k0)
      if (s + 2 < 8) ldf(pk, wave*8 + s + 2, lane, fa);
      float k1[16]; tile_keys(fb, bqh, bql, sq, wave*8 + s + 1, lhi, k1);
      HIST2(k1)
    }
  }
  __syncthreads();
  if (tid < 32) {
    unsigned c = below1s[tid], b = 255u, fnd = 0;
    #pragma unroll 1
    for (int i = 0; i < 256; ++i) {
      c += hist[i][tid];
      if (!fnd && c >= KP1) { b = (unsigned)i; fnd = 1; }
    }
    const unsigned bu = (bin1s[tid] << 24) | (b << 16) | 0xFFFFu;
    // decode transformed-u32 bound back to float (bit31 set => orig positive)
    boundf[tid] = __uint_as_float((bu & 0x80000000u) ? (bu & 0x7fffffffu) : ~bu);
  }
  __syncthreads();
  const float bfq = boundf[qcol];

  // ---- phase 3: full scan + collect ----
  {
    F8 fa, fb;
    ldf(pk, wave*64, lane, fa);
    #pragma unroll 1
    for (int s = 0; s < 64; s += 2) {
      ldf(pk, wave*64 + s + 1, lane, fb);
      float k0[16]; tile_keys(fa, bqh, bql, sq, wave*64 + s, lhi, k0);
      COLLECT(k0, wave*64 + s)
      if (s + 2 < 64) ldf(pk, wave*64 + s + 2, lane, fa);
      float k1[16]; tile_keys(fb, bqh, bql, sq, wave*64 + s + 1, lhi, k1);
      COLLECT(k1, wave*64 + s + 1)
    }
  }
  __syncthreads();
  if (tid < 32) gcnt[qt*32 + tid] = min(ccnt[tid], (unsigned)CAP);
}

// ---------------- select: one wave per query, exact lex (key, idx) top-17 ----------------
__global__ __launch_bounds__(256) void k_select(const unsigned long long* __restrict__ coll,
    const unsigned* __restrict__ gcnt, int* __restrict__ idxout) {
  const int gw = (blockIdx.x*256 + threadIdx.x) >> 6;   // query = global wave id
  const int lane = threadIdx.x & 63;
  const int m = min((int)gcnt[gw], CAP);
  const unsigned long long* cp = coll + (size_t)gw*CAP;
  unsigned long long a0,a1,a2,a3,a4,a5,a6;
  a0 = (lane       < m) ? cp[lane      ] : ~0ULL;
  a1 = (lane +  64 < m) ? cp[lane +  64] : ~0ULL;
  a2 = (lane + 128 < m) ? cp[lane + 128] : ~0ULL;
  a3 = (lane + 192 < m) ? cp[lane + 192] : ~0ULL;
  a4 = (lane + 256 < m) ? cp[lane + 256] : ~0ULL;
  a5 = (lane + 320 < m) ? cp[lane + 320] : ~0ULL;
  a6 = (lane + 384 < m) ? cp[lane + 384] : ~0ULL;
  #define CS(X,Y) { if (Y < X) { const unsigned long long t_ = X; X = Y; Y = t_; } }
  CS(a0,a1) CS(a2,a3) CS(a4,a5)
  CS(a1,a2) CS(a3,a4) CS(a5,a6)
  CS(a0,a1) CS(a2,a3) CS(a4,a5)
  CS(a1,a2) CS(a3,a4) CS(a5,a6)
  CS(a0,a1) CS(a2,a3) CS(a4,a5)
  CS(a1,a2) CS(a3,a4) CS(a5,a6)
  CS(a0,a1) CS(a2,a3) CS(a4,a5)
  #undef CS
  #pragma unroll
  for (int p = 0; p < KP1; ++p) {
    unsigned long long w = a0;
    #pragma unroll
    for (int d = 1; d < 64; d <<= 1) {
      const unsigned long long o = __shfl_xor(w, d);
      w = o < w ? o : w;
    }
    if (lane == 0) idxout[gw*KP1 + p] = (int)(unsigned)(w & 0xffffffffULL);
    if (a0 == w) { a0=a1; a1=a2; a2=a3; a3=a4; a4=a5; a5=a6; a6=~0ULL; }  // keys distinct: one popper
  }
}

// ---------------- column stats (sum, sumsq) ----------------
__global__ __launch_bounds__(256) void k_colstats(const float* __restrict__ x, const int rows,
    float* __restrict__ s, float* __restrict__ s2) {
  __shared__ float ls[4][64], ls2[4][64];
  const int tid = threadIdx.x;
  const int c = tid & 63, g = tid >> 6;
  float a = 0.f, b = 0.f;
  for (int r = blockIdx.x*4 + g; r < rows; r += 1024) {
    const float v = x[(size_t)r*64 + c];
    a += v; b = fmaf(v, v, b);
  }
  ls[g][c] = a; ls2[g][c] = b;
  __syncthreads();
  if (tid < 64) {
    atomicAdd(&s[tid],  ls[0][tid]+ls[1][tid]+ls[2][tid]+ls[3][tid]);
    atomicAdd(&s2[tid], ls2[0][tid]+ls2[1][tid]+ls2[2][tid]+ls2[3][tid]);
  }
}

// 64-col FMA against LDS weight row (broadcast reads)
__device__ __forceinline__ void fmarow(float (&acc)[64], const float (*ws)[64], int kk, float xv) {
  #pragma unroll
  for (int cq = 0; cq < 16; ++cq) {
    const float4 w4 = *(const float4*)&ws[kk][cq*4];
    acc[cq*4]   = fmaf(xv, w4.x, acc[cq*4]);
    acc[cq*4+1] = fmaf(xv, w4.y, acc[cq*4+1]);
    acc[cq*4+2] = fmaf(xv, w4.z, acc[cq*4+2]);
    acc[cq*4+3] = fmaf(xv, w4.w, acc[cq*4+3]);
  }
}

// ---------------- msg linear-1: y = [h[to] | h[frm]] @ W1 + b1 ----------------
__global__ __launch_bounds__(256) void k_mlpA_gather(const float* __restrict__ h,
    const int* __restrict__ idx, const float* __restrict__ W1, const float* __restrict__ b1,
    float* __restrict__ y) {
  __shared__ __align__(16) float ws[128][64];
  const int tid = threadIdx.x;
  for (int t = tid; t < 128*64/4; t += 256) ((float4*)ws)[t] = ((const float4*)W1)[t];
  __syncthreads();
  const int e = blockIdx.x*256 + tid;
  const int i = e & (NN-1);
  const int k = e >> 14;
  const int to = idx[i*KP1 + k + 1];
  const int fr = idx[i*KP1];
  float acc[64];
  #pragma unroll
  for (int c = 0; c < 64; ++c) acc[c] = b1[c];
  const float4* xa = (const float4*)(h + (size_t)to*64);
  #pragma unroll 2
  for (int kb = 0; kb < 16; ++kb) {
    const float4 x4 = xa[kb];
    fmarow(acc, ws, kb*4,   x4.x); fmarow(acc, ws, kb*4+1, x4.y);
    fmarow(acc, ws, kb*4+2, x4.z); fmarow(acc, ws, kb*4+3, x4.w);
  }
  const float4* xb = (const float4*)(h + (size_t)fr*64);
  #pragma unroll 2
  for (int kb = 0; kb < 16; ++kb) {
    const float4 x4 = xb[kb];
    fmarow(acc, ws, 64+kb*4,   x4.x); fmarow(acc, ws, 64+kb*4+1, x4.y);
    fmarow(acc, ws, 64+kb*4+2, x4.z); fmarow(acc, ws, 64+kb*4+3, x4.w);
  }
  float4* yo = (float4*)(y + (size_t)e*64);
  #pragma unroll
  for (int q = 0; q < 16; ++q) yo[q] = make_float4(acc[4*q], acc[4*q+1], acc[4*q+2], acc[4*q+3]);
}

// ---------------- upd linear-1: y = [h | agg] @ W1 + b1 ----------------
__global__ __launch_bounds__(256) void k_mlpA_cat(const float* __restrict__ h,
    const float* __restrict__ agg, const float* __restrict__ W1, const float* __restrict__ b1,
    float* __restrict__ y) {
  __shared__ __align__(16) float ws[128][64];
  const int tid = threadIdx.x;
  for (int t = tid; t < 128*64/4; t += 256) ((float4*)ws)[t] = ((const float4*)W1)[t];
  __syncthreads();
  const int n = blockIdx.x*256 + tid;
  float acc[64];
  #pragma unroll
  for (int c = 0; c < 64; ++c) acc[c] = b1[c];
  const float4* xa = (const float4*)(h + (size_t)n*64);
  #pragma unroll 2
  for (int kb = 0; kb < 16; ++kb) {
    const float4 x4 = xa[kb];
    fmarow(acc, ws, kb*4,   x4.x); fmarow(acc, ws, kb*4+1, x4.y);
    fmarow(acc, ws, kb*4+2, x4.z); fmarow(acc, ws, kb*4+3, x4.w);
  }
  const float4* xb = (const float4*)(agg + (size_t)n*64);
  #pragma unroll 2
  for (int kb = 0; kb < 16; ++kb) {
    const float4 x4 = xb[kb];
    fmarow(acc, ws, 64+kb*4,   x4.x); fmarow(acc, ws, 64+kb*4+1, x4.y);
    fmarow(acc, ws, 64+kb*4+2, x4.z); fmarow(acc, ws, 64+kb*4+3, x4.w);
  }
  float4* yo = (float4*)(y + (size_t)n*64);
  #pragma unroll
  for (int q = 0; q < 16; ++q) yo[q] = make_float4(acc[4*q], acc[4*q+1], acc[4*q+2], acc[4*q+3]);
}

// ---------------- linear-2 with fused BN+ReLU on input, IN-PLACE on y ----------------
__global__ __launch_bounds__(256) void k_mlpB(float* __restrict__ y,
    const float* __restrict__ s, const float* __restrict__ s2,
    const float* __restrict__ g, const float* __restrict__ be,
    const float* __restrict__ W2, const float* __restrict__ b2, const float invR) {
  __shared__ __align__(16) float ws[64][64];
  __shared__ float sc[64], sh[64];
  const int tid = threadIdx.x;
  for (int t = tid; t < 64*64/4; t += 256) ((float4*)ws)[t] = ((const float4*)W2)[t];
  if (tid < 64) {
    const float m = s[tid]*invR;
    const float v = fmaxf(s2[tid]*invR - m*m, 0.f);
    const float scv = g[tid]*rsqrtf(v + 1e-5f);
    sc[tid] = scv; sh[tid] = be[tid] - m*scv;
  }
  __syncthreads();
  const int e = blockIdx.x*256 + tid;
  float acc[64];
  #pragma unroll
  for (int c = 0; c < 64; ++c) acc[c] = b2[c];
  const float4* yr = (const float4*)(y + (size_t)e*64);
  #pragma unroll 2
  for (int kb = 0; kb < 16; ++kb) {
    const float4 x4 = yr[kb];
    const int k0 = kb*4;
    fmarow(acc, ws, k0,   fmaxf(fmaf(x4.x, sc[k0],   sh[k0]),   0.f));
    fmarow(acc, ws, k0+1, fmaxf(fmaf(x4.y, sc[k0+1], sh[k0+1]), 0.f));
    fmarow(acc, ws, k0+2, fmaxf(fmaf(x4.z, sc[k0+2], sh[k0+2]), 0.f));
    fmarow(acc, ws, k0+3, fmaxf(fmaf(x4.w, sc[k0+3], sh[k0+3]), 0.f));
  }
  float4* yo = (float4*)(y + (size_t)e*64);
  #pragma unroll
  for (int q = 0; q < 16; ++q) yo[q] = make_float4(acc[4*q], acc[4*q+1], acc[4*q+2], acc[4*q+3]);
}

// ---------------- msg final BN+ReLU + scatter-add ----------------
__global__ __launch_bounds__(256) void k_msgC(const float* __restrict__ y,
    const float* __restrict__ s, const float* __restrict__ s2,
    const float* __restrict__ g, const float* __restrict__ be,
    const int* __restrict__ idx, float* __restrict__ agg, const float invR) {
  __shared__ float sc[64], sh[64];
  const int tid = threadIdx.x;
  if (tid < 64) {
    const float m = s[tid]*invR;
    const float v = fmaxf(s2[tid]*invR - m*m, 0.f);
    const float scv = g[tid]*rsqrtf(v + 1e-5f);
    sc[tid] = scv; sh[tid] = be[tid] - m*scv;
  }
  __syncthreads();
  const int t = blockIdx.x*256 + tid;    // over E*64
  const int e = t >> 6, c = t & 63;
  const int i = e & (NN-1), k = e >> 14;
  const int to = idx[i*KP1 + k + 1];
  const float v = fmaxf(fmaf(y[t], sc[c], sh[c]), 0.f);
  atomicAdd(&agg[(size_t)to*64 + c], v);
}

// ---------------- upd final BN+ReLU + residual ----------------
__global__ __launch_bounds__(256) void k_updC(const float* __restrict__ y,
    const float* __restrict__ s, const float* __restrict__ s2,
    const float* __restrict__ g, const float* __restrict__ be,
    float* __restrict__ h, const float invR) {
  __shared__ float sc[64], sh[64];
  const int tid = threadIdx.x;
  if (tid < 64) {
    const float m = s[tid]*invR;
    const float v = fmaxf(s2[tid]*invR - m*m, 0.f);
    const float scv = g[tid]*rsqrtf(v + 1e-5f);
    sc[tid] = scv; sh[tid] = be[tid] - m*scv;
  }
  __syncthreads();
  const int t = blockIdx.x*256 + tid;    // over N*64
  const int c = t & 63;
  h[t] += fmaxf(fmaf(y[t], sc[c], sh[c]), 0.f);
}

// ---------------- out = mean(h) @ predW + predb ----------------
__global__ void k_final(const float* __restrict__ hsum, const float* __restrict__ pW,
                        const float* __restrict__ pb, float* __restrict__ out) {
  const int c = threadIdx.x;   // 64
  float v = hsum[c] * (1.f/(float)NN) * pW[c];
  #pragma unroll
  for (int m = 32; m >= 1; m >>= 1) v += __shfl_xor(v, m, 64);
  if (c == 0) out[0] = v + pb[0];
}

extern "C" void kernel_launch(void* const* d_in, const int* in_sizes, int n_in,
                              void* d_out, int out_size, void* d_ws, size_t ws_size,
                              hipStream_t stream) {
  const float* pos   = (const float*)d_in[0];
  const float* linW  = (const float*)d_in[1];
  const float* linb  = (const float*)d_in[2];
  const float* predW = (const float*)d_in[3];
  const float* predb = (const float*)d_in[4];
  const float* mW1 = (const float*)d_in[5];
  const float* mb1 = (const float*)d_in[6];
  const float* mg1 = (const float*)d_in[7];
  const float* mbe1= (const float*)d_in[8];
  const float* mW2 = (const float*)d_in[9];
  const float* mb2 = (const float*)d_in[10];
  const float* mg2 = (const float*)d_in[11];
  const float* mbe2= (const float*)d_in[12];
  const float* uW1 = (const float*)d_in[13];
  const float* ub1 = (const float*)d_in[14];
  const float* ug1 = (const float*)d_in[15];
  const float* ube1= (const float*)d_in[16];
  const float* uW2 = (const float*)d_in[17];
  const float* ub2 = (const float*)d_in[18];
  const float* ug2 = (const float*)d_in[19];
  const float* ube2= (const float*)d_in[20];

  // workspace layout (~80 MB)
  float* h     = (float*)d_ws;                    // N*64
  float* sq    = h + (size_t)NN*64;               // N
  float* agg   = sq + NN;                         // N*64
  float* ubuf  = agg + (size_t)NN*64;             // N*64
  float* stats = ubuf + (size_t)NN*64;            // 640
  int*   idx   = (int*)(stats + 640);             // N*17
  float* yb    = (float*)(idx + (size_t)NN*KP1);  // E*64 fp32 (67 MB)
  // knn-phase scratch aliased into yb (dead once MLP phase writes yb): ~63 MB
  ushort* pk = (ushort*)yb;                                     // (N/32)*4096 bf16 = 4 MB
  unsigned long long* coll = (unsigned long long*)(pk + (size_t)(NN/32)*4096); // N*CAP u64
  unsigned* gcnt   = (unsigned*)(coll + (size_t)NN*CAP);        // N

  k_lin_in<<<NN*64/256, 256, 0, stream>>>(pos, linW, linb, h);
  for (int l = 0; l < 4; ++l) {
    k_sqnorm<<<NN/256, 256, 0, stream>>>(h, sq);
    k_prep<<<(NN/32)*4*64/256, 256, 0, stream>>>(h, pk);
    k_knn<<<NN/32, 512, 0, stream>>>(pk, sq, coll, gcnt);
    k_select<<<NN/4, 256, 0, stream>>>(coll, gcnt, idx);
    hipMemsetAsync(stats, 0, 640*sizeof(float), stream);
    hipMemsetAsync(agg, 0, (size_t)NN*64*sizeof(float), stream);
    // msg MLP over E edges
    k_mlpA_gather<<<EE/256, 256, 0, stream>>>(h, idx, mW1 + l*8192, mb1 + l*64, yb);
    k_colstats<<<256, 256, 0, stream>>>(yb, EE, stats, stats+64);
    k_mlpB<<<EE/256, 256, 0, stream>>>(yb, stats, stats+64, mg1 + l*64, mbe1 + l*64,
                                       mW2 + l*4096, mb2 + l*64, 1.f/(float)EE);
    k_colstats<<<256, 256, 0, stream>>>(yb, EE, stats+128, stats+192);
    k_msgC<<<EE*64/256, 256, 0, stream>>>(yb, stats+128, stats+192, mg2 + l*64, mbe2 + l*64,
                                          idx, agg, 1.f/(float)EE);
    // upd MLP over N nodes
    k_mlpA_cat<<<NN/256, 256, 0, stream>>>(h, agg, uW1 + l*8192, ub1 + l*64, ubuf);
    k_colstats<<<256, 256, 0, stream>>>(ubuf, NN, stats+256, stats+320);
    k_mlpB<<<NN/256, 256, 0, stream>>>(ubuf, stats+256, stats+320, ug1 + l*64, ube1 + l*64,
                                       uW2 + l*4096, ub2 + l*64, 1.f/(float)NN);
    k_colstats<<<256, 256, 0, stream>>>(ubuf, NN, stats+384, stats+448);
    k_updC<<<NN*64/256, 256, 0, stream>>>(ubuf, stats+384, stats+448, ug2 + l*64, ube2 + l*64,
                                          h, 1.f/(float)NN);
  }
  hipMemsetAsync(stats+512, 0, 128*sizeof(float), stream);
  k_colstats<<<256, 256, 0, stream>>>(h, NN, stats+512, stats+576);
  k_final<<<1, 64, 0, stream>>>(stats+512, predW, predb, (float*)d_out);
}